// Round 12
// baseline (519.704 us; speedup 1.0000x reference)
//
#include <hip/hip_runtime.h>
#include <cstdint>
#include <cstddef>

// MLSMPO on MI355X — R12 (= R11 + alphaC scope fix): barrier-free k_prod/k_prodF.
// Whole 9-step A-stream (144KB) staged into LDS once (2-phase: 0-2 then 3-8),
// then waves free-run with ZERO in-loop barriers/waitcnts — ds_read/VALU/MFMA
// overlap across the 8 staggered waves instead of lockstep phases.

typedef float    f32x16 __attribute__((ext_vector_type(16)));
typedef _Float16 f16x8  __attribute__((ext_vector_type(8)));
typedef __fp16   fp16x2 __attribute__((ext_vector_type(2)));
typedef _Float16 h2_t   __attribute__((ext_vector_type(2)));
typedef const void __attribute__((address_space(1))) gas_t;
typedef void       __attribute__((address_space(3))) las_t;

union U16  { uint4 u; f16x8 h; };
union B16u { uint32_t u[4]; f16x8 h; };
union H2U  { fp16x2 h; uint32_t u; };

__device__ __forceinline__ uint32_t pkf16(float a, float b){   // RTZ (hot path only)
  H2U z; z.h = __builtin_amdgcn_cvt_pkrtz(a, b); return z.u;
}
__device__ __forceinline__ uint32_t pkmul(uint32_t a, uint32_t b){
  H2U x, y, r; x.u = a; y.u = b;
  r.h = x.h * y.h; return r.u;
}
__device__ __forceinline__ uint32_t packh2(float a, float b){  // RTNE
  union { _Float16 h[2]; uint32_t u; } z;
  z.h[0] = (_Float16)a; z.h[1] = (_Float16)b; return z.u;
}
__device__ __forceinline__ float fdot2f(uint32_t wa, uint32_t wb, float acc){
  union U { uint32_t u; h2_t h; };
  U a, b; a.u = wa; b.u = wb;
  return __builtin_amdgcn_fdot2(a.h, b.h, acc, false);
}

#define REC 17408   // bytes per stream step: 16KB A-frags + 1KB v-record

// ---------------- stream builders (verified R5) ----------------
__global__ void k_build(const float* __restrict__ Wmid, const float* __restrict__ Wout,
                        char* __restrict__ S, int J, int n, int dirR){
  int tid = blockIdx.x*256 + threadIdx.x;
  if (tid >= n*4096) return;
  int gt = tid >> 12, r = tid & 4095;
  int f = r >> 8, ln = (r >> 2) & 63, dw = r & 3;
  int s = f >> 1, m = f & 1;
  int row = m*32 + (ln & 31);
  int kb = s*16 + (ln >> 5)*8 + dw*2;
  int p = kb >> 6, q = kb & 63;
  int jj = gt/9, pos = gt - jj*9;
  int j = dirR ? (J-1-jj) : jj;
  int outs = dirR ? 8 : 0;
  float w[2];
  #pragma unroll
  for (int k2 = 0; k2 < 2; ++k2){
    int qq = q + k2;
    int d = dirR ? row : qq;
    int e = dirR ? qq : row;
    float val;
    if (pos == outs){
      const float* src = Wout + ((((size_t)j*64 + d)*64 + e)*2 + p)*9;
      val = 0.f;
      #pragma unroll
      for (int ff = 0; ff < 9; ++ff) val += src[ff];
      if (d == e) val -= 0.8f;
    } else {
      int mi = dirR ? (7 - pos) : (pos - 1);
      val = Wmid[((((size_t)j*8 + mi)*64 + d)*64 + e)*2 + p];
    }
    w[k2] = val;
  }
  uint32_t* S32 = (uint32_t*)(S + (size_t)gt*REC);
  S32[f*256 + ln*4 + dw] = packh2(w[0]*256.f, w[1]*256.f);
}

__global__ void k_buildF(const float* __restrict__ Wm, char* __restrict__ S){
  int tid = blockIdx.x*256 + threadIdx.x;
  if (tid >= 80*4096) return;
  int gt = tid >> 12, r = tid & 4095;
  int f = r >> 8, ln = (r >> 2) & 63, dw = r & 3;
  int s = f >> 1, m = f & 1;
  int row = m*32 + (ln & 31);
  int kb = s*16 + (ln >> 5)*8 + dw*2;
  int p = kb >> 6, q = kb & 63;
  float w[2];
  #pragma unroll
  for (int k2 = 0; k2 < 2; ++k2){
    int d = q + k2, e = row;
    w[k2] = Wm[(((size_t)gt*64 + d)*64 + e)*2 + p];
  }
  uint32_t* S32 = (uint32_t*)(S + (size_t)gt*REC);
  S32[f*256 + ln*4 + dw] = packh2(w[0]*256.f, w[1]*256.f);
}

__global__ void k_vrec(const float2* __restrict__ v, char* __restrict__ S,
                       int n, int nv, int mode){
  int tid = blockIdx.x*256 + threadIdx.x;
  if (tid >= n*128) return;
  int gt = tid >> 7, b = tid & 127;
  int site = (mode == 0) ? gt : (mode == 1) ? (n-1-gt) : (gt+1);
  *(float2*)(S + (size_t)gt*REC + 16384 + b*8) = v[(size_t)b*nv + site];
}

// ---------------- patch embed ----------------
__global__ void k_embed(const float* __restrict__ img, int Wd, int PG,
                        float2* __restrict__ outv){
  int tid = blockIdx.x*256 + threadIdx.x;
  int NP = PG*PG;
  if (tid >= 128*NP) return;
  int b = tid / NP, s = tid - b*NP;
  int pi = s / PG, pj = s - pi*PG;
  const float* base = img + (size_t)b*Wd*Wd + (size_t)(3*pi)*Wd + 3*pj;
  float cs = 0.f, sn = 0.f;
  #pragma unroll
  for (int r = 0; r < 3; ++r){
    #pragma unroll
    for (int c = 0; c < 3; ++c){
      float x = base[r*Wd + c];
      float s_, c_; sincosf(1.5707963267948966f*x, &s_, &c_);
      cs += c_; sn += s_;
    }
  }
  cs *= (1.f/9.f); sn *= (1.f/9.f);
  float rn = rsqrtf(cs*cs + sn*sn);
  float2 v; v.x = cs*rn; v.y = sn*rn;
  outv[tid] = v;
}

// ---------------- shared MFMA helpers ----------------
__device__ __forceinline__ void stage17(const char* g, char* l){
  #pragma unroll
  for (int i = 0; i < 17; ++i)
    __builtin_amdgcn_global_load_lds((gas_t*)(const void*)(g + i*1024),
                                     (las_t*)(void*)(l + i*1024), 16, 0, 0);
}

#define MKBASE(acc, bd) do { \
  uint32_t P0 = pkf16(acc[0],acc[1]),  P1 = pkf16(acc[2],acc[3]); \
  uint32_t P2 = pkf16(acc[4],acc[5]),  P3 = pkf16(acc[6],acc[7]); \
  uint32_t Q0 = (uint32_t)__shfl_xor((int)P0, 32); \
  uint32_t Q1 = (uint32_t)__shfl_xor((int)P1, 32); \
  uint32_t Q2 = (uint32_t)__shfl_xor((int)P2, 32); \
  uint32_t Q3 = (uint32_t)__shfl_xor((int)P3, 32); \
  bd[0] = hlo ? P0 : Q2;  bd[1] = hlo ? P1 : Q3; \
  bd[2] = hlo ? Q0 : P2;  bd[3] = hlo ? Q1 : P3; \
  uint32_t R0 = pkf16(acc[8],acc[9]),   R1 = pkf16(acc[10],acc[11]); \
  uint32_t R2 = pkf16(acc[12],acc[13]), R3 = pkf16(acc[14],acc[15]); \
  uint32_t T0 = (uint32_t)__shfl_xor((int)R0, 32); \
  uint32_t T1 = (uint32_t)__shfl_xor((int)R1, 32); \
  uint32_t T2 = (uint32_t)__shfl_xor((int)R2, 32); \
  uint32_t T3 = (uint32_t)__shfl_xor((int)R3, 32); \
  bd[4] = hlo ? R0 : T2;  bd[5] = hlo ? R1 : T3; \
  bd[6] = hlo ? T0 : R2;  bd[7] = hlo ? T1 : R3; \
} while(0)

#define MFMA8(slotp) do { \
  const uint4* fr_ = (const uint4*)(slotp); \
  _Pragma("unroll") \
  for (int s_ = 0; s_ < 8; ++s_){ \
    const int sl_ = s_ & 3; \
    const uint32_t* bb_ = (sl_ < 2) ? bd0 : bd1; \
    const int off_ = (sl_ & 1)*4; \
    const uint32_t scl_ = (s_ < 4) ? px : py; \
    B16u bs_; \
    _Pragma("unroll") \
    for (int dw_ = 0; dw_ < 4; ++dw_) bs_.u[dw_] = pkmul(bb_[off_+dw_], scl_); \
    U16 fa0_, fa1_; \
    fa0_.u = fr_[(2*s_)*64 + ln]; \
    fa1_.u = fr_[(2*s_+1)*64 + ln]; \
    acc0 = __builtin_amdgcn_mfma_f32_32x32x16_f16(fa0_.h, bs_.h, acc0, 0, 0, 0); \
    acc1 = __builtin_amdgcn_mfma_f32_32x32x16_f16(fa1_.h, bs_.h, acc1, 0, 0, 0); \
  } \
} while(0)

// 4-tile MFMA body shared by k_prod/k_prodF
#define PROD_SLOOP(buf) do { \
  const uint4* fr = (const uint4*)(buf); \
  _Pragma("unroll") \
  for (int s = 0; s < 8; ++s){ \
    const int sl = s & 3; \
    const uint32_t scl = (s < 4) ? px : py; \
    const int off = (sl & 1)*4; \
    U16 f0, f1; \
    f0.u = fr[(2*s)*64 + ln]; \
    f1.u = fr[(2*s+1)*64 + ln]; \
    { \
      const uint32_t* bb = (sl < 2) ? bl0 : bh0; \
      B16u bs; \
      _Pragma("unroll") \
      for (int dw = 0; dw < 4; ++dw) bs.u[dw] = pkmul(bb[off+dw], scl); \
      a00 = __builtin_amdgcn_mfma_f32_32x32x16_f16(f0.h, bs.h, a00, 0, 0, 0); \
      a10 = __builtin_amdgcn_mfma_f32_32x32x16_f16(f1.h, bs.h, a10, 0, 0, 0); \
    } \
    { \
      const uint32_t* bb = (sl < 2) ? bl1 : bh1; \
      B16u bs; \
      _Pragma("unroll") \
      for (int dw = 0; dw < 4; ++dw) bs.u[dw] = pkmul(bb[off+dw], scl); \
      a01 = __builtin_amdgcn_mfma_f32_32x32x16_f16(f0.h, bs.h, a01, 0, 0, 0); \
      a11 = __builtin_amdgcn_mfma_f32_32x32x16_f16(f1.h, bs.h, a11, 0, 0, 0); \
    } \
  } \
} while(0)

#define PROD_INIT_I() do { \
  _Pragma("unroll") \
  for (int i = 0; i < 16; ++i){ a00[i]=0.f; a01[i]=0.f; a10[i]=0.f; a11[i]=0.f; } \
  if (((i32 >> 2) & 1) == h){ \
    int rr0 = (i32 & 3) | ((i32 >> 3) << 2); \
    _Pragma("unroll") \
    for (int rr = 0; rr < 16; ++rr) \
      if (rr == rr0){ a00[rr] = 1.f; a11[rr] = 1.f; } \
  } \
} while(0)

#define PROD_WRITEOUT(ob, diagc) do { \
  _Pragma("unroll") \
  for (int x = 0; x < 2; ++x){ \
    _Pragma("unroll") \
    for (int y = 0; y < 2; ++y){ \
      const f32x16& A = (x==0) ? (y==0 ? a00 : a01) : (y==0 ? a10 : a11); \
      int C = y*32 + i32; \
      _Pragma("unroll") \
      for (int r = 0; r < 16; ++r){ \
        int R = x*32 + (r & 3) + 8*(r >> 2) + 4*h; \
        float val = (A[r] - ((R == C) ? (diagc) : 0.f))*256.f; \
        float oth = __shfl_xor(val, 1); \
        if (!(ln & 1)){ \
          uint32_t dwv = packh2(val, oth); \
          *(uint32_t*)((ob) + R*128 + ((C*2) ^ ((R & 7) << 4))) = dwv; \
        } \
      } \
    } \
  } \
} while(0)

// one chain step: repack state, optional t==0 alpha-scale, 32 MFMA
#define PROD_STEP(t, doalpha) do { \
  uint32_t px = pkf16(vv[t].x*INV, vv[t].x*INV); \
  uint32_t py = pkf16(vv[t].y*INV, vv[t].y*INV); \
  uint32_t bl0[8], bh0[8], bl1[8], bh1[8]; \
  MKBASE(a00, bl0); MKBASE(a10, bh0); \
  MKBASE(a01, bl1); MKBASE(a11, bh1); \
  if (doalpha){ \
    _Pragma("unroll") \
    for (int i = 0; i < 16; ++i){ \
      a00[i] *= alphaC; a01[i] *= alphaC; a10[i] *= alphaC; a11[i] *= alphaC; \
    } \
  } \
  PROD_SLOOP(lds + (size_t)(t)*16384); \
} while(0)

// ---------------- group-product production (layers) ----------------
// XCD-remapped grid; whole 9-step stream in LDS (144KB); two stage phases,
// two barriers total, compute loop runs with NO barriers or waitcnts.
__global__ __launch_bounds__(512, 1) void k_prod(
    const char* __restrict__ sL, const char* __restrict__ sR,
    const float2* __restrict__ v, char* __restrict__ Tn, char* __restrict__ Wn,
    int J){
  __shared__ __align__(16) char lds[9*16384];
  const int ln = threadIdx.x & 63, w = threadIdx.x >> 6;
  const int wid = (blockIdx.x & 7)*(J*4) + (blockIdx.x >> 3);
  const int bg = wid & 15;
  const int pair = wid >> 4;
  const int dir = pair & 1, j = pair >> 1;
  const int b = bg*8 + w;
  const bool hlo = (ln < 32);
  const int h = ln >> 5, i32 = ln & 31;
  const float INV = 1.f/256.f;
  const char* stream = dir ? sR : sL;
  const int n = J*9;

  float2 vv[9];
  {
    const float2* vbase = v + (size_t)b*n + j*9;
    #pragma unroll
    for (int t = 0; t < 9; ++t) vv[t] = vbase[dir ? (9 - t) : t];
  }
  const float alphaC = (dir && j == J-1) ? 1.0f : 0.8f*(vv[0].x + vv[0].y);
  if (dir && j == J-1){ vv[0].x = 0.f; vv[0].y = 0.f; }

  auto gtf = [&](int t) -> int {
    int g = dir ? ((J-2-j)*9 + 8 + t) : (j*9 + t);
    return g < 0 ? 0 : g;
  };
  auto stage = [&](int t){
    const char* g0 = stream + (size_t)gtf(t)*REC + (size_t)(2*w)*1024 + (size_t)ln*16;
    char* l0 = lds + (size_t)t*16384;
    __builtin_amdgcn_global_load_lds((gas_t*)(const void*)g0,
                                     (las_t*)(void*)(l0 + 2*w*1024), 16, 0, 0);
    __builtin_amdgcn_global_load_lds((gas_t*)(const void*)(g0 + 1024),
                                     (las_t*)(void*)(l0 + (2*w+1)*1024), 16, 0, 0);
  };

  f32x16 a00, a01, a10, a11;
  PROD_INIT_I();

  stage(0); stage(1); stage(2);
  asm volatile("s_waitcnt vmcnt(0)" ::: "memory");
  __builtin_amdgcn_s_barrier();
  #pragma unroll
  for (int t = 3; t < 9; ++t) stage(t);

  PROD_STEP(0, true);
  PROD_STEP(1, false);
  PROD_STEP(2, false);
  asm volatile("s_waitcnt vmcnt(0)" ::: "memory");
  __builtin_amdgcn_s_barrier();
  #pragma unroll
  for (int t = 3; t < 9; ++t) PROD_STEP(t, false);

  char* ob = (dir ? Wn : Tn) + ((size_t)b*J + j)*8192;
  PROD_WRITEOUT(ob, alphaC);
}

// ---------------- final-layer group products: G_g^T, 10 groups x 8 mids ----
__global__ __launch_bounds__(512, 1) void k_prodF(
    const char* __restrict__ sF, const float2* __restrict__ vF,
    char* __restrict__ GF){
  __shared__ __align__(16) char lds[8*16384];
  const int ln = threadIdx.x & 63, w = threadIdx.x >> 6;
  const int wid = (blockIdx.x & 7)*20 + (blockIdx.x >> 3);
  const int bg = wid & 15, g = wid >> 4;
  const int b = bg*8 + w;
  const bool hlo = (ln < 32);
  const int h = ln >> 5, i32 = ln & 31;
  const float INV = 1.f/256.f;
  const float alphaC = 1.0f;   // unused (doalpha=false paths); scope for PROD_STEP

  float2 vv[8];
  {
    const float2* vbase = vF + (size_t)b*81 + g*8 + 1;
    #pragma unroll
    for (int t = 0; t < 8; ++t) vv[t] = vbase[t];
  }
  auto stage = [&](int t){
    const char* g0 = sF + (size_t)(g*8 + t)*REC + (size_t)(2*w)*1024 + (size_t)ln*16;
    char* l0 = lds + (size_t)t*16384;
    __builtin_amdgcn_global_load_lds((gas_t*)(const void*)g0,
                                     (las_t*)(void*)(l0 + 2*w*1024), 16, 0, 0);
    __builtin_amdgcn_global_load_lds((gas_t*)(const void*)(g0 + 1024),
                                     (las_t*)(void*)(l0 + (2*w+1)*1024), 16, 0, 0);
  };

  f32x16 a00, a01, a10, a11;
  PROD_INIT_I();

  stage(0); stage(1); stage(2);
  asm volatile("s_waitcnt vmcnt(0)" ::: "memory");
  __builtin_amdgcn_s_barrier();
  #pragma unroll
  for (int t = 3; t < 8; ++t) stage(t);

  PROD_STEP(0, false);
  PROD_STEP(1, false);
  PROD_STEP(2, false);
  asm volatile("s_waitcnt vmcnt(0)" ::: "memory");
  __builtin_amdgcn_s_barrier();
  #pragma unroll
  for (int t = 3; t < 8; ++t) PROD_STEP(t, false);

  char* ob = GF + ((size_t)b*10 + g)*8192;
  PROD_WRITEOUT(ob, 1.0f);
}

// ---------------- group-level env scans (layers), depth-3 ----------------
__global__ __launch_bounds__(64, 1) void k_gscan(
    const char* __restrict__ Tn, const char* __restrict__ Wn,
    const float2* __restrict__ v,
    float* __restrict__ Lout, float* __restrict__ Rout, int J){
  __shared__ __align__(16) char slot[4][8192];
  __shared__ __align__(16) float2 vvs[81];
  __shared__ __align__(16) uint32_t pk32[32];
  const int ln = threadIdx.x;
  const int dir = blockIdx.x >> 7;
  const int b = blockIdx.x & 127;
  const float INV = 1.f/256.f;
  const char* P = (dir ? Wn : Tn) + (size_t)b*J*8192;

  for (int g = ln; g < J; g += 64) vvs[g] = v[(size_t)b*(J*9) + (size_t)g*9];

  auto JD = [&](int g){ return dir ? (J-1-g) : g; };
  auto stage8 = [&](int jx, int sl){
    const char* g0 = P + (size_t)jx*8192 + (size_t)ln*16;
    #pragma unroll
    for (int i = 0; i < 8; ++i)
      __builtin_amdgcn_global_load_lds((gas_t*)(const void*)(g0 + i*1024),
                                       (las_t*)(void*)(slot[sl] + i*1024), 16, 0, 0);
  };

  stage8(JD(0), 0);
  stage8(JD(1 < J-1 ? 1 : J-1), 1);
  stage8(JD(2 < J-1 ? 2 : J-1), 2);

  float st = (ln == 0) ? 1.f : 0.f;
  const uint32_t swz = (uint32_t)(ln & 7) << 4;

  #pragma unroll 1
  for (int g = 0; g < J; ++g){
    const int j = JD(g);
    asm volatile("s_waitcnt vmcnt(16)" ::: "memory");
    if (!dir) Lout[((size_t)j*128 + b)*64 + ln] = st;
    {
      int gn = (g+3 > J-1) ? (J-1) : (g+3);
      stage8(JD(gn), (g+3) & 3);
    }

    float c;
    if (dir) c = (j < J-1) ? 0.8f*(vvs[j+1].x + vvs[j+1].y) : 1.0f;
    else     c = 0.8f*(vvs[j].x + vvs[j].y);

    {
      float o = __shfl_xor(st, 1);
      pk32[ln>>1] = (ln & 1) ? packh2(o, st) : packh2(st, o);
    }
    const char* sp = slot[g & 3] + (size_t)ln*128;
    const uint4* lp = (const uint4*)pk32;
    float acc = 0.f;
    #pragma unroll
    for (int m = 0; m < 8; ++m){
      uint4 q = lp[m];
      uint4 ww = *(const uint4*)(sp + ((m*16) ^ swz));
      acc = fdot2f(ww.x, q.x, acc); acc = fdot2f(ww.y, q.y, acc);
      acc = fdot2f(ww.z, q.z, acc); acc = fdot2f(ww.w, q.w, acc);
    }
    st = c*st + acc*INV;
    if (dir) Rout[((size_t)j*128 + b)*64 + ln] = st;
  }
}

// ---------------- final-layer group scan, depth-3 ----------
__global__ __launch_bounds__(64, 1) void k_fscan(
    const char* __restrict__ GF, const float* __restrict__ A0f,
    const float2* __restrict__ vF, float* __restrict__ outp){
  __shared__ __align__(16) char slot[4][8192];
  __shared__ __align__(16) uint32_t pk[10][32];
  const int ln = threadIdx.x;
  const int b = blockIdx.x;
  const float INV = 1.f/256.f;
  const char* P = GF + (size_t)b*10*8192;

  float2 v0 = vF[(size_t)b*81];
  float u[10];
  #pragma unroll
  for (int o = 0; o < 10; ++o)
    u[o] = v0.x*A0f[(ln*2+0)*10 + o] + v0.y*A0f[(ln*2+1)*10 + o];

  auto stage8 = [&](int g, int sl){
    const char* g0 = P + (size_t)g*8192 + (size_t)ln*16;
    #pragma unroll
    for (int i = 0; i < 8; ++i)
      __builtin_amdgcn_global_load_lds((gas_t*)(const void*)(g0 + i*1024),
                                       (las_t*)(void*)(slot[sl] + i*1024), 16, 0, 0);
  };

  stage8(0, 0);
  stage8(1, 1);
  stage8(2, 2);
  const uint32_t swz = (uint32_t)(ln & 7) << 4;

  #pragma unroll 1
  for (int g = 0; g < 10; ++g){
    asm volatile("s_waitcnt vmcnt(16)" ::: "memory");
    {
      int gn = (g+3 > 9) ? 9 : (g+3);
      stage8(gn, (g+3) & 3);
    }
    #pragma unroll
    for (int o = 0; o < 10; ++o){
      float ot = __shfl_xor(u[o], 1);
      pk[o][ln>>1] = (ln & 1) ? packh2(ot, u[o]) : packh2(u[o], ot);
    }
    const char* sp = slot[g & 3] + (size_t)ln*128;
    uint4 wr[8];
    #pragma unroll
    for (int m = 0; m < 8; ++m) wr[m] = *(const uint4*)(sp + ((m*16) ^ swz));
    #pragma unroll
    for (int o = 0; o < 10; ++o){
      const uint4* lp = (const uint4*)pk[o];
      float acc = 0.f;
      #pragma unroll
      for (int m = 0; m < 8; ++m){
        uint4 q = lp[m];
        acc = fdot2f(wr[m].x, q.x, acc); acc = fdot2f(wr[m].y, q.y, acc);
        acc = fdot2f(wr[m].z, q.z, acc); acc = fdot2f(wr[m].w, q.w, acc);
      }
      u[o] += acc*INV;
    }
  }
  if (ln == 0){
    #pragma unroll
    for (int o = 0; o < 10; ++o) outp[(size_t)b*10 + o] = u[o];
  }
}

// ---------------- R5 MFMA scan (fallback) ----------------
__global__ __launch_bounds__(64, 1) void k_scan_m(
    const char* __restrict__ sL, const char* __restrict__ sR,
    float* __restrict__ Lout, float* __restrict__ Rout, int J, int n){
  __shared__ __align__(16) char lds[4*REC];
  const int ln = threadIdx.x;
  const int wg = blockIdx.x;
  const int dir = wg >> 2;
  const int colbase = (wg & 3)*32;
  const char* stream = dir ? sR : sL;
  float* Sout = dir ? Rout : Lout;
  const int outs = dir ? 8 : 0;
  const int b = colbase + (ln & 31);
  const bool hlo = (ln < 32);
  const int h4 = (ln >> 5)*4;
  const float INV = 1.f/256.f;

  f32x16 acc0, acc1;
  #pragma unroll
  for (int i = 0; i < 16; ++i){ acc0[i] = 0.f; acc1[i] = 0.f; }
  if (hlo) acc0[0] = 1.f;

  const char* gsrc = stream + (size_t)ln*16;
  stage17(gsrc,           lds);
  stage17(gsrc + REC,     lds + REC);
  stage17(gsrc + 2*REC,   lds + 2*REC);

  int pos = 0, jj = 0;
  for (int t = 0; t < n; ++t){
    asm volatile("s_waitcnt vmcnt(34)" ::: "memory");
    const char* slot = lds + (size_t)(t & 3)*REC;
    float2 vv = *(const float2*)(slot + 16384 + b*8);
    int tn = t + 3; if (tn > n-1) tn = n-1;
    stage17(gsrc + (size_t)tn*REC, lds + (size_t)(tn & 3)*REC);

    uint32_t px = pkf16(vv.x*INV, vv.x*INV);
    uint32_t py = pkf16(vv.y*INV, vv.y*INV);
    uint32_t bd0[8], bd1[8];
    MKBASE(acc0, bd0);
    MKBASE(acc1, bd1);

    if (pos == outs){
      int jdx = dir ? (J-1-jj) : jj;
      float* dst = Sout + ((size_t)jdx*128 + b)*64;
      #pragma unroll
      for (int q = 0; q < 4; ++q){
        float4 f0; f0.x = acc0[4*q]; f0.y = acc0[4*q+1]; f0.z = acc0[4*q+2]; f0.w = acc0[4*q+3];
        *(float4*)(dst + 8*q + h4) = f0;
        float4 f1; f1.x = acc1[4*q]; f1.y = acc1[4*q+1]; f1.z = acc1[4*q+2]; f1.w = acc1[4*q+3];
        *(float4*)(dst + 32 + 8*q + h4) = f1;
      }
      float alpha = 0.8f*(vv.x + vv.y);
      #pragma unroll
      for (int i = 0; i < 16; ++i){ acc0[i] *= alpha; acc1[i] *= alpha; }
    }

    MFMA8(slot);

    ++pos; if (pos == 9){ pos = 0; ++jj; }
  }
}

// ---------------- final layer R5 (fallback) ----------------
__global__ __launch_bounds__(64, 1) void k_final_m(
    const char* __restrict__ sF, const float* __restrict__ A0f,
    const float2* __restrict__ vF, float* __restrict__ outp){
  __shared__ __align__(16) char lds[4*REC];
  const int ln = threadIdx.x;
  const int wg = blockIdx.x;
  const int o = wg >> 2;
  const int b = (wg & 3)*32 + (ln & 31);
  const bool hlo = (ln < 32);
  const int h4 = (ln >> 5)*4;
  const float INV = 1.f/256.f;

  float2 v0 = vF[(size_t)b*81];
  f32x16 acc0, acc1;
  #pragma unroll
  for (int rg = 0; rg < 16; ++rg){
    int row0 = (rg & 3) + 8*(rg >> 2) + h4;
    acc0[rg] = v0.x*A0f[(row0*2+0)*10 + o] + v0.y*A0f[(row0*2+1)*10 + o];
    int row1 = row0 + 32;
    acc1[rg] = v0.x*A0f[(row1*2+0)*10 + o] + v0.y*A0f[(row1*2+1)*10 + o];
  }
  asm volatile("s_waitcnt vmcnt(0)" ::: "memory");

  const char* gsrc = sF + (size_t)ln*16;
  stage17(gsrc,         lds);
  stage17(gsrc + REC,   lds + REC);
  stage17(gsrc + 2*REC, lds + 2*REC);

  const int n = 80;
  for (int t = 0; t < n; ++t){
    asm volatile("s_waitcnt vmcnt(34)" ::: "memory");
    const char* slot = lds + (size_t)(t & 3)*REC;
    float2 vv = *(const float2*)(slot + 16384 + b*8);
    int tn = t + 3; if (tn > n-1) tn = n-1;
    stage17(gsrc + (size_t)tn*REC, lds + (size_t)(tn & 3)*REC);

    uint32_t px = pkf16(vv.x*INV, vv.x*INV);
    uint32_t py = pkf16(vv.y*INV, vv.y*INV);
    uint32_t bd0[8], bd1[8];
    MKBASE(acc0, bd0);
    MKBASE(acc1, bd1);
    MFMA8(slot);
  }
  if (hlo) outp[(size_t)b*10 + o] = acc0[0];
}

// ---------------- epilogue: 32b x 8 e-octants, grid (J,4) ----------------
template<bool EMB>
__global__ __launch_bounds__(256) void k_out(
    const float* __restrict__ Wout, const float* __restrict__ Lbuf,
    const float* __restrict__ Rbuf, const float2* __restrict__ v, int n,
    float* __restrict__ hout, float2* __restrict__ vF){
  __shared__ float tile[8][64][20];
  __shared__ float Lsh[32][65];
  const int j = blockIdx.x, bh = blockIdx.y;
  const int q = threadIdx.x >> 5, bl = threadIdx.x & 31;
  const int b = bh*32 + bl;
  for (int idx = threadIdx.x; idx < 32*64; idx += 256){
    int r = idx >> 6, d = idx & 63;
    Lsh[r][d] = Lbuf[((size_t)j*128 + bh*32 + r)*64 + d];
  }
  float Rr[8];
  {
    const float4* Rp = (const float4*)(Rbuf + ((size_t)j*128 + b)*64 + q*8);
    ((float4*)Rr)[0] = Rp[0];
    ((float4*)Rr)[1] = Rp[1];
  }
  float acc[18];
  #pragma unroll
  for (int k = 0; k < 18; ++k) acc[k] = 0.f;
  __syncthreads();
  for (int c = 0; c < 8; ++c){
    #pragma unroll
    for (int k = 0; k < 2; ++k){
      int pi = threadIdx.x*2 + k;
      int d8 = pi >> 6, e = pi & 63;
      const float* src = Wout + ((size_t)(j*64 + c*8 + d8)*64 + e)*18;
      float* dst = &tile[d8][e][0];
      #pragma unroll
      for (int mm = 0; mm < 18; ++mm) dst[mm] = src[mm];
    }
    __syncthreads();
    #pragma unroll 1
    for (int d8 = 0; d8 < 8; ++d8){
      float lw = Lsh[bl][c*8 + d8];
      #pragma unroll
      for (int i = 0; i < 8; ++i){
        int e = q*8 + i;
        float wbe = lw * Rr[i];
        const float* tp = &tile[d8][e][0];
        float4 t0 = *(const float4*)(tp);
        float4 t1 = *(const float4*)(tp+4);
        float4 t2 = *(const float4*)(tp+8);
        float4 t3 = *(const float4*)(tp+12);
        float2 t4 = *(const float2*)(tp+16);
        acc[0]  += wbe*t0.x; acc[1]  += wbe*t0.y; acc[2]  += wbe*t0.z; acc[3]  += wbe*t0.w;
        acc[4]  += wbe*t1.x; acc[5]  += wbe*t1.y; acc[6]  += wbe*t1.z; acc[7]  += wbe*t1.w;
        acc[8]  += wbe*t2.x; acc[9]  += wbe*t2.y; acc[10] += wbe*t2.z; acc[11] += wbe*t2.w;
        acc[12] += wbe*t3.x; acc[13] += wbe*t3.y; acc[14] += wbe*t3.z; acc[15] += wbe*t3.w;
        acc[16] += wbe*t4.x; acc[17] += wbe*t4.y;
      }
    }
    __syncthreads();
  }
  float* red = &tile[0][0][0];
  #pragma unroll
  for (int k = 0; k < 18; ++k) red[((size_t)q*32 + bl)*20 + k] = acc[k];
  __syncthreads();
  if (q == 0){
    float s[18];
    #pragma unroll
    for (int k = 0; k < 18; ++k){
      float t = 0.f;
      #pragma unroll
      for (int g = 0; g < 8; ++g) t += red[((size_t)g*32 + bl)*20 + k];
      s[k] = t;
    }
    float2 vo = v[(size_t)b*n + j*9];
    #pragma unroll
    for (int f = 0; f < 9; ++f){
      float val = vo.x*s[f] + vo.y*s[9+f];
      if (EMB){
        float s_, c_; sincosf(1.5707963267948966f*val, &s_, &c_);
        float2 e2; e2.x = c_; e2.y = s_;
        vF[(size_t)b*81 + j*9 + f] = e2;
      } else {
        hout[(size_t)b*729 + j*9 + f] = val;
      }
    }
  }
}

// ---------------- host ----------------
extern "C" void kernel_launch(void* const* d_in, const int* in_sizes, int n_in,
                              void* d_out, int out_size, void* d_ws, size_t ws_size,
                              hipStream_t stream){
  const float* x     = (const float*)d_in[0];
  const float* Wout0 = (const float*)d_in[1];
  const float* Wmid0 = (const float*)d_in[2];
  const float* Wout1 = (const float*)d_in[3];
  const float* Wmid1 = (const float*)d_in[4];
  const float* A0f   = (const float*)d_in[5];
  const float* WmidF = (const float*)d_in[6];
  float* outp = (float*)d_out;

  char* ws = (char*)d_ws;
  size_t off = 0;
  auto alloc = [&](size_t bytes) -> char* {
    char* p = ws + off;
    off = (off + bytes + 255) & ~(size_t)255;
    return p;
  };
  char* S0L = alloc((size_t)729*REC);
  char* S0R = alloc((size_t)729*REC);
  char* S1L = alloc((size_t)81*REC);
  char* S1R = alloc((size_t)81*REC);
  char* SF  = alloc((size_t)80*REC);
  float2* v0 = (float2*)alloc((size_t)128*729*8);
  float2* v1 = (float2*)alloc((size_t)128*81*8);
  float2* vF = (float2*)alloc((size_t)128*81*8);
  float* L0 = (float*)alloc((size_t)81*128*64*4);
  float* R0 = (float*)alloc((size_t)81*128*64*4);
  float* L1 = (float*)alloc((size_t)9*128*64*4);
  float* R1 = (float*)alloc((size_t)9*128*64*4);
  float* h1 = (float*)alloc((size_t)128*729*4);
  char* Tn1 = alloc((size_t)128*81*8192);
  char* Wn1 = alloc((size_t)128*81*8192);
  size_t need_r7 = off;
  char* Tn2 = alloc((size_t)128*9*8192);
  char* Wn2 = alloc((size_t)128*9*8192);
  char* GF  = alloc((size_t)128*10*8192);
  size_t need_full = off;
  bool full = (ws_size >= need_full);
  bool grp1 = (ws_size >= need_r7);
  (void)in_sizes; (void)n_in; (void)out_size;

  // streams
  k_build <<<1296,  256, 0, stream>>>(Wmid1, Wout1, S1L, 9, 81, 0);
  k_build <<<1296,  256, 0, stream>>>(Wmid1, Wout1, S1R, 9, 81, 1);
  k_buildF<<<1280,  256, 0, stream>>>(WmidF, SF);
  k_build<<<11664, 256, 0, stream>>>(Wmid0, Wout0, S0L, 81, 729, 0);
  k_build<<<11664, 256, 0, stream>>>(Wmid0, Wout0, S0R, 81, 729, 1);

  // layer 1
  k_embed<<<365, 256, 0, stream>>>(x, 81, 27, v0);
  if (grp1){
    k_prod <<<2592, 512, 0, stream>>>(S0L, S0R, v0, Tn1, Wn1, 81);
    k_gscan<<<256, 64, 0, stream>>>(Tn1, Wn1, v0, L0, R0, 81);
  } else {
    k_vrec <<<365, 256, 0, stream>>>(v0, S0L, 729, 729, 0);
    k_vrec <<<365, 256, 0, stream>>>(v0, S0R, 729, 729, 1);
    k_scan_m<<<8, 64, 0, stream>>>(S0L, S0R, L0, R0, 81, 729);
  }
  k_out<false><<<dim3(81,4), 256, 0, stream>>>(Wout0, L0, R0, v0, 729, h1, (float2*)nullptr);

  // layer 2
  k_embed<<<41, 256, 0, stream>>>(h1, 27, 9, v1);
  if (full){
    k_prod <<<288, 512, 0, stream>>>(S1L, S1R, v1, Tn2, Wn2, 9);
    k_gscan<<<256, 64, 0, stream>>>(Tn2, Wn2, v1, L1, R1, 9);
  } else {
    k_vrec <<<41, 256, 0, stream>>>(v1, S1L, 81, 81, 0);
    k_vrec <<<41, 256, 0, stream>>>(v1, S1R, 81, 81, 1);
    k_scan_m<<<8, 64, 0, stream>>>(S1L, S1R, L1, R1, 9, 81);
  }
  k_out<true><<<dim3(9,4), 256, 0, stream>>>(Wout1, L1, R1, v1, 81, (float*)nullptr, vF);

  // final layer
  if (full){
    k_prodF<<<160, 512, 0, stream>>>(SF, vF, GF);
    k_fscan<<<128, 64, 0, stream>>>(GF, A0f, vF, outp);
  } else {
    k_vrec <<<40, 256, 0, stream>>>(vF, SF, 80, 81, 2);
    k_final_m<<<40, 64, 0, stream>>>(SF, A0f, vF, outp);
  }
}

// Round 14
// 502.624 us; speedup vs baseline: 1.0340x; 1.0340x over previous
//
#include <hip/hip_runtime.h>
#include <cstdint>
#include <cstddef>

// MLSMPO on MI355X — R14: R13 with CORRECTED permlane32_swap mapping.
// True semantics (derived from the verified attn idiom): swap(A,B) exchanges
// A.hi with B.lo, returning {newA={A.lo,B.lo}, newB={A.hi,B.hi}}.
// So: r = swap(P0,P2); bd[0]=r[0] (rows 0,1|8,9); bd[2]=r[1] (rows 4,5|12,13).

typedef float    f32x16 __attribute__((ext_vector_type(16)));
typedef _Float16 f16x8  __attribute__((ext_vector_type(8)));
typedef __fp16   fp16x2 __attribute__((ext_vector_type(2)));
typedef _Float16 h2_t   __attribute__((ext_vector_type(2)));
typedef unsigned int uint32x2_t __attribute__((ext_vector_type(2)));
typedef const void __attribute__((address_space(1))) gas_t;
typedef void       __attribute__((address_space(3))) las_t;

union U16  { uint4 u; f16x8 h; };
union B16u { uint32_t u[4]; f16x8 h; };
union H2U  { fp16x2 h; uint32_t u; };

__device__ __forceinline__ uint32_t pkf16(float a, float b){   // RTZ (hot path only)
  H2U z; z.h = __builtin_amdgcn_cvt_pkrtz(a, b); return z.u;
}
__device__ __forceinline__ uint32_t pkmul(uint32_t a, uint32_t b){
  H2U x, y, r; x.u = a; y.u = b;
  r.h = x.h * y.h; return r.u;
}
__device__ __forceinline__ uint32_t packh2(float a, float b){  // RTNE
  union { _Float16 h[2]; uint32_t u; } z;
  z.h[0] = (_Float16)a; z.h[1] = (_Float16)b; return z.u;
}
__device__ __forceinline__ float fdot2f(uint32_t wa, uint32_t wb, float acc){
  union U { uint32_t u; h2_t h; };
  U a, b; a.u = wa; b.u = wb;
  return __builtin_amdgcn_fdot2(a.h, b.h, acc, false);
}

#define REC 17408   // bytes per stream step: 16KB A-frags + 1KB v-record

// ---------------- stream builders (verified R5) ----------------
__global__ void k_build(const float* __restrict__ Wmid, const float* __restrict__ Wout,
                        char* __restrict__ S, int J, int n, int dirR){
  int tid = blockIdx.x*256 + threadIdx.x;
  if (tid >= n*4096) return;
  int gt = tid >> 12, r = tid & 4095;
  int f = r >> 8, ln = (r >> 2) & 63, dw = r & 3;
  int s = f >> 1, m = f & 1;
  int row = m*32 + (ln & 31);
  int kb = s*16 + (ln >> 5)*8 + dw*2;
  int p = kb >> 6, q = kb & 63;
  int jj = gt/9, pos = gt - jj*9;
  int j = dirR ? (J-1-jj) : jj;
  int outs = dirR ? 8 : 0;
  float w[2];
  #pragma unroll
  for (int k2 = 0; k2 < 2; ++k2){
    int qq = q + k2;
    int d = dirR ? row : qq;
    int e = dirR ? qq : row;
    float val;
    if (pos == outs){
      const float* src = Wout + ((((size_t)j*64 + d)*64 + e)*2 + p)*9;
      val = 0.f;
      #pragma unroll
      for (int ff = 0; ff < 9; ++ff) val += src[ff];
      if (d == e) val -= 0.8f;
    } else {
      int mi = dirR ? (7 - pos) : (pos - 1);
      val = Wmid[((((size_t)j*8 + mi)*64 + d)*64 + e)*2 + p];
    }
    w[k2] = val;
  }
  uint32_t* S32 = (uint32_t*)(S + (size_t)gt*REC);
  S32[f*256 + ln*4 + dw] = packh2(w[0]*256.f, w[1]*256.f);
}

__global__ void k_buildF(const float* __restrict__ Wm, char* __restrict__ S){
  int tid = blockIdx.x*256 + threadIdx.x;
  if (tid >= 80*4096) return;
  int gt = tid >> 12, r = tid & 4095;
  int f = r >> 8, ln = (r >> 2) & 63, dw = r & 3;
  int s = f >> 1, m = f & 1;
  int row = m*32 + (ln & 31);
  int kb = s*16 + (ln >> 5)*8 + dw*2;
  int p = kb >> 6, q = kb & 63;
  float w[2];
  #pragma unroll
  for (int k2 = 0; k2 < 2; ++k2){
    int d = q + k2, e = row;
    w[k2] = Wm[(((size_t)gt*64 + d)*64 + e)*2 + p];
  }
  uint32_t* S32 = (uint32_t*)(S + (size_t)gt*REC);
  S32[f*256 + ln*4 + dw] = packh2(w[0]*256.f, w[1]*256.f);
}

__global__ void k_vrec(const float2* __restrict__ v, char* __restrict__ S,
                       int n, int nv, int mode){
  int tid = blockIdx.x*256 + threadIdx.x;
  if (tid >= n*128) return;
  int gt = tid >> 7, b = tid & 127;
  int site = (mode == 0) ? gt : (mode == 1) ? (n-1-gt) : (gt+1);
  *(float2*)(S + (size_t)gt*REC + 16384 + b*8) = v[(size_t)b*nv + site];
}

// ---------------- patch embed ----------------
__global__ void k_embed(const float* __restrict__ img, int Wd, int PG,
                        float2* __restrict__ outv){
  int tid = blockIdx.x*256 + threadIdx.x;
  int NP = PG*PG;
  if (tid >= 128*NP) return;
  int b = tid / NP, s = tid - b*NP;
  int pi = s / PG, pj = s - pi*PG;
  const float* base = img + (size_t)b*Wd*Wd + (size_t)(3*pi)*Wd + 3*pj;
  float cs = 0.f, sn = 0.f;
  #pragma unroll
  for (int r = 0; r < 3; ++r){
    #pragma unroll
    for (int c = 0; c < 3; ++c){
      float x = base[r*Wd + c];
      float s_, c_; sincosf(1.5707963267948966f*x, &s_, &c_);
      cs += c_; sn += s_;
    }
  }
  cs *= (1.f/9.f); sn *= (1.f/9.f);
  float rn = rsqrtf(cs*cs + sn*sn);
  float2 v; v.x = cs*rn; v.y = sn*rn;
  outv[tid] = v;
}

// ---------------- shared MFMA helpers ----------------
__device__ __forceinline__ void stage17(const char* g, char* l){
  #pragma unroll
  for (int i = 0; i < 17; ++i)
    __builtin_amdgcn_global_load_lds((gas_t*)(const void*)(g + i*1024),
                                     (las_t*)(void*)(l + i*1024), 16, 0, 0);
}

// D(f32x16 tile) -> 8 B-frag base dwords via permlane32_swap (VALU, no LDS).
// swap(A,B): A.hi <-> B.lo; returns {newA={A.lo,B.lo}, newB={A.hi,B.hi}}.
// bd[0] = {P0.lo, P2.lo} (rows 0,1|8,9); bd[2] = {P0.hi, P2.hi} (rows 4,5|12,13).
#define MKBASE(acc, bd) do { \
  uint32_t P0 = pkf16(acc[0],acc[1]),  P1 = pkf16(acc[2],acc[3]); \
  uint32_t P2 = pkf16(acc[4],acc[5]),  P3 = pkf16(acc[6],acc[7]); \
  { uint32x2_t r_ = __builtin_amdgcn_permlane32_swap(P0, P2, false, false); \
    bd[0] = r_[0]; bd[2] = r_[1]; } \
  { uint32x2_t r_ = __builtin_amdgcn_permlane32_swap(P1, P3, false, false); \
    bd[1] = r_[0]; bd[3] = r_[1]; } \
  uint32_t R0 = pkf16(acc[8],acc[9]),   R1 = pkf16(acc[10],acc[11]); \
  uint32_t R2 = pkf16(acc[12],acc[13]), R3 = pkf16(acc[14],acc[15]); \
  { uint32x2_t r_ = __builtin_amdgcn_permlane32_swap(R0, R2, false, false); \
    bd[4] = r_[0]; bd[6] = r_[1]; } \
  { uint32x2_t r_ = __builtin_amdgcn_permlane32_swap(R1, R3, false, false); \
    bd[5] = r_[0]; bd[7] = r_[1]; } \
} while(0)

#define MFMA8(slotp) do { \
  const uint4* fr_ = (const uint4*)(slotp); \
  _Pragma("unroll") \
  for (int s_ = 0; s_ < 8; ++s_){ \
    const int sl_ = s_ & 3; \
    const uint32_t* bb_ = (sl_ < 2) ? bd0 : bd1; \
    const int off_ = (sl_ & 1)*4; \
    const uint32_t scl_ = (s_ < 4) ? px : py; \
    B16u bs_; \
    _Pragma("unroll") \
    for (int dw_ = 0; dw_ < 4; ++dw_) bs_.u[dw_] = pkmul(bb_[off_+dw_], scl_); \
    U16 fa0_, fa1_; \
    fa0_.u = fr_[(2*s_)*64 + ln]; \
    fa1_.u = fr_[(2*s_+1)*64 + ln]; \
    acc0 = __builtin_amdgcn_mfma_f32_32x32x16_f16(fa0_.h, bs_.h, acc0, 0, 0, 0); \
    acc1 = __builtin_amdgcn_mfma_f32_32x32x16_f16(fa1_.h, bs_.h, acc1, 0, 0, 0); \
  } \
} while(0)

// 4-tile MFMA body shared by k_prod/k_prodF
#define PROD_SLOOP(buf) do { \
  const uint4* fr = (const uint4*)(buf); \
  _Pragma("unroll") \
  for (int s = 0; s < 8; ++s){ \
    const int sl = s & 3; \
    const uint32_t scl = (s < 4) ? px : py; \
    const int off = (sl & 1)*4; \
    U16 f0, f1; \
    f0.u = fr[(2*s)*64 + ln]; \
    f1.u = fr[(2*s+1)*64 + ln]; \
    { \
      const uint32_t* bb = (sl < 2) ? bl0 : bh0; \
      B16u bs; \
      _Pragma("unroll") \
      for (int dw = 0; dw < 4; ++dw) bs.u[dw] = pkmul(bb[off+dw], scl); \
      a00 = __builtin_amdgcn_mfma_f32_32x32x16_f16(f0.h, bs.h, a00, 0, 0, 0); \
      a10 = __builtin_amdgcn_mfma_f32_32x32x16_f16(f1.h, bs.h, a10, 0, 0, 0); \
    } \
    { \
      const uint32_t* bb = (sl < 2) ? bl1 : bh1; \
      B16u bs; \
      _Pragma("unroll") \
      for (int dw = 0; dw < 4; ++dw) bs.u[dw] = pkmul(bb[off+dw], scl); \
      a01 = __builtin_amdgcn_mfma_f32_32x32x16_f16(f0.h, bs.h, a01, 0, 0, 0); \
      a11 = __builtin_amdgcn_mfma_f32_32x32x16_f16(f1.h, bs.h, a11, 0, 0, 0); \
    } \
  } \
} while(0)

#define PROD_INIT_I() do { \
  _Pragma("unroll") \
  for (int i = 0; i < 16; ++i){ a00[i]=0.f; a01[i]=0.f; a10[i]=0.f; a11[i]=0.f; } \
  if (((i32 >> 2) & 1) == h){ \
    int rr0 = (i32 & 3) | ((i32 >> 3) << 2); \
    _Pragma("unroll") \
    for (int rr = 0; rr < 16; ++rr) \
      if (rr == rr0){ a00[rr] = 1.f; a11[rr] = 1.f; } \
  } \
} while(0)

#define PROD_WRITEOUT(ob, diagc) do { \
  _Pragma("unroll") \
  for (int x = 0; x < 2; ++x){ \
    _Pragma("unroll") \
    for (int y = 0; y < 2; ++y){ \
      const f32x16& A = (x==0) ? (y==0 ? a00 : a01) : (y==0 ? a10 : a11); \
      int C = y*32 + i32; \
      _Pragma("unroll") \
      for (int r = 0; r < 16; ++r){ \
        int R = x*32 + (r & 3) + 8*(r >> 2) + 4*h; \
        float val = (A[r] - ((R == C) ? (diagc) : 0.f))*256.f; \
        float oth = __shfl_xor(val, 1); \
        if (!(ln & 1)){ \
          uint32_t dwv = packh2(val, oth); \
          *(uint32_t*)((ob) + R*128 + ((C*2) ^ ((R & 7) << 4))) = dwv; \
        } \
      } \
    } \
  } \
} while(0)

// one chain step: repack state, optional t==0 alpha-scale, 32 MFMA
#define PROD_STEP(t, doalpha) do { \
  uint32_t px = pkf16(vv[t].x*INV, vv[t].x*INV); \
  uint32_t py = pkf16(vv[t].y*INV, vv[t].y*INV); \
  uint32_t bl0[8], bh0[8], bl1[8], bh1[8]; \
  MKBASE(a00, bl0); MKBASE(a10, bh0); \
  MKBASE(a01, bl1); MKBASE(a11, bh1); \
  if (doalpha){ \
    _Pragma("unroll") \
    for (int i = 0; i < 16; ++i){ \
      a00[i] *= alphaC; a01[i] *= alphaC; a10[i] *= alphaC; a11[i] *= alphaC; \
    } \
  } \
  PROD_SLOOP(lds + (size_t)(t)*16384); \
} while(0)

// ---------------- group-product production (layers) ----------------
// XCD-remapped grid; whole 9-step stream in LDS (144KB); two stage phases,
// two barriers total, compute loop runs with NO barriers or waitcnts.
__global__ __launch_bounds__(512, 1) void k_prod(
    const char* __restrict__ sL, const char* __restrict__ sR,
    const float2* __restrict__ v, char* __restrict__ Tn, char* __restrict__ Wn,
    int J){
  __shared__ __align__(16) char lds[9*16384];
  const int ln = threadIdx.x & 63, w = threadIdx.x >> 6;
  const int wid = (blockIdx.x & 7)*(J*4) + (blockIdx.x >> 3);
  const int bg = wid & 15;
  const int pair = wid >> 4;
  const int dir = pair & 1, j = pair >> 1;
  const int b = bg*8 + w;
  const int h = ln >> 5, i32 = ln & 31;
  const float INV = 1.f/256.f;
  const char* stream = dir ? sR : sL;
  const int n = J*9;

  float2 vv[9];
  {
    const float2* vbase = v + (size_t)b*n + j*9;
    #pragma unroll
    for (int t = 0; t < 9; ++t) vv[t] = vbase[dir ? (9 - t) : t];
  }
  const float alphaC = (dir && j == J-1) ? 1.0f : 0.8f*(vv[0].x + vv[0].y);
  if (dir && j == J-1){ vv[0].x = 0.f; vv[0].y = 0.f; }

  auto gtf = [&](int t) -> int {
    int g = dir ? ((J-2-j)*9 + 8 + t) : (j*9 + t);
    return g < 0 ? 0 : g;
  };
  auto stage = [&](int t){
    const char* g0 = stream + (size_t)gtf(t)*REC + (size_t)(2*w)*1024 + (size_t)ln*16;
    char* l0 = lds + (size_t)t*16384;
    __builtin_amdgcn_global_load_lds((gas_t*)(const void*)g0,
                                     (las_t*)(void*)(l0 + 2*w*1024), 16, 0, 0);
    __builtin_amdgcn_global_load_lds((gas_t*)(const void*)(g0 + 1024),
                                     (las_t*)(void*)(l0 + (2*w+1)*1024), 16, 0, 0);
  };

  f32x16 a00, a01, a10, a11;
  PROD_INIT_I();

  stage(0); stage(1); stage(2);
  asm volatile("s_waitcnt vmcnt(0)" ::: "memory");
  __builtin_amdgcn_s_barrier();
  #pragma unroll
  for (int t = 3; t < 9; ++t) stage(t);

  PROD_STEP(0, true);
  PROD_STEP(1, false);
  PROD_STEP(2, false);
  asm volatile("s_waitcnt vmcnt(0)" ::: "memory");
  __builtin_amdgcn_s_barrier();
  #pragma unroll
  for (int t = 3; t < 9; ++t) PROD_STEP(t, false);

  char* ob = (dir ? Wn : Tn) + ((size_t)b*J + j)*8192;
  PROD_WRITEOUT(ob, alphaC);
}

// ---------------- final-layer group products: G_g^T, 10 groups x 8 mids ----
__global__ __launch_bounds__(512, 1) void k_prodF(
    const char* __restrict__ sF, const float2* __restrict__ vF,
    char* __restrict__ GF){
  __shared__ __align__(16) char lds[8*16384];
  const int ln = threadIdx.x & 63, w = threadIdx.x >> 6;
  const int wid = (blockIdx.x & 7)*20 + (blockIdx.x >> 3);
  const int bg = wid & 15, g = wid >> 4;
  const int b = bg*8 + w;
  const int h = ln >> 5, i32 = ln & 31;
  const float INV = 1.f/256.f;
  const float alphaC = 1.0f;   // unused (doalpha=false paths); scope for PROD_STEP

  float2 vv[8];
  {
    const float2* vbase = vF + (size_t)b*81 + g*8 + 1;
    #pragma unroll
    for (int t = 0; t < 8; ++t) vv[t] = vbase[t];
  }
  auto stage = [&](int t){
    const char* g0 = sF + (size_t)(g*8 + t)*REC + (size_t)(2*w)*1024 + (size_t)ln*16;
    char* l0 = lds + (size_t)t*16384;
    __builtin_amdgcn_global_load_lds((gas_t*)(const void*)g0,
                                     (las_t*)(void*)(l0 + 2*w*1024), 16, 0, 0);
    __builtin_amdgcn_global_load_lds((gas_t*)(const void*)(g0 + 1024),
                                     (las_t*)(void*)(l0 + (2*w+1)*1024), 16, 0, 0);
  };

  f32x16 a00, a01, a10, a11;
  PROD_INIT_I();

  stage(0); stage(1); stage(2);
  asm volatile("s_waitcnt vmcnt(0)" ::: "memory");
  __builtin_amdgcn_s_barrier();
  #pragma unroll
  for (int t = 3; t < 8; ++t) stage(t);

  PROD_STEP(0, false);
  PROD_STEP(1, false);
  PROD_STEP(2, false);
  asm volatile("s_waitcnt vmcnt(0)" ::: "memory");
  __builtin_amdgcn_s_barrier();
  #pragma unroll
  for (int t = 3; t < 8; ++t) PROD_STEP(t, false);

  char* ob = GF + ((size_t)b*10 + g)*8192;
  PROD_WRITEOUT(ob, 1.0f);
}

// ---------------- group-level env scans (layers), depth-3 ----------------
__global__ __launch_bounds__(64, 1) void k_gscan(
    const char* __restrict__ Tn, const char* __restrict__ Wn,
    const float2* __restrict__ v,
    float* __restrict__ Lout, float* __restrict__ Rout, int J){
  __shared__ __align__(16) char slot[4][8192];
  __shared__ __align__(16) float2 vvs[81];
  __shared__ __align__(16) uint32_t pk32[32];
  const int ln = threadIdx.x;
  const int dir = blockIdx.x >> 7;
  const int b = blockIdx.x & 127;
  const float INV = 1.f/256.f;
  const char* P = (dir ? Wn : Tn) + (size_t)b*J*8192;

  for (int g = ln; g < J; g += 64) vvs[g] = v[(size_t)b*(J*9) + (size_t)g*9];

  auto JD = [&](int g){ return dir ? (J-1-g) : g; };
  auto stage8 = [&](int jx, int sl){
    const char* g0 = P + (size_t)jx*8192 + (size_t)ln*16;
    #pragma unroll
    for (int i = 0; i < 8; ++i)
      __builtin_amdgcn_global_load_lds((gas_t*)(const void*)(g0 + i*1024),
                                       (las_t*)(void*)(slot[sl] + i*1024), 16, 0, 0);
  };

  stage8(JD(0), 0);
  stage8(JD(1 < J-1 ? 1 : J-1), 1);
  stage8(JD(2 < J-1 ? 2 : J-1), 2);

  float st = (ln == 0) ? 1.f : 0.f;
  const uint32_t swz = (uint32_t)(ln & 7) << 4;

  #pragma unroll 1
  for (int g = 0; g < J; ++g){
    const int j = JD(g);
    asm volatile("s_waitcnt vmcnt(16)" ::: "memory");
    if (!dir) Lout[((size_t)j*128 + b)*64 + ln] = st;
    {
      int gn = (g+3 > J-1) ? (J-1) : (g+3);
      stage8(JD(gn), (g+3) & 3);
    }

    float c;
    if (dir) c = (j < J-1) ? 0.8f*(vvs[j+1].x + vvs[j+1].y) : 1.0f;
    else     c = 0.8f*(vvs[j].x + vvs[j].y);

    {
      float o = __shfl_xor(st, 1);
      pk32[ln>>1] = (ln & 1) ? packh2(o, st) : packh2(st, o);
    }
    const char* sp = slot[g & 3] + (size_t)ln*128;
    const uint4* lp = (const uint4*)pk32;
    float acc = 0.f;
    #pragma unroll
    for (int m = 0; m < 8; ++m){
      uint4 q = lp[m];
      uint4 ww = *(const uint4*)(sp + ((m*16) ^ swz));
      acc = fdot2f(ww.x, q.x, acc); acc = fdot2f(ww.y, q.y, acc);
      acc = fdot2f(ww.z, q.z, acc); acc = fdot2f(ww.w, q.w, acc);
    }
    st = c*st + acc*INV;
    if (dir) Rout[((size_t)j*128 + b)*64 + ln] = st;
  }
}

// ---------------- final-layer group scan, depth-3 ----------
__global__ __launch_bounds__(64, 1) void k_fscan(
    const char* __restrict__ GF, const float* __restrict__ A0f,
    const float2* __restrict__ vF, float* __restrict__ outp){
  __shared__ __align__(16) char slot[4][8192];
  __shared__ __align__(16) uint32_t pk[10][32];
  const int ln = threadIdx.x;
  const int b = blockIdx.x;
  const float INV = 1.f/256.f;
  const char* P = GF + (size_t)b*10*8192;

  float2 v0 = vF[(size_t)b*81];
  float u[10];
  #pragma unroll
  for (int o = 0; o < 10; ++o)
    u[o] = v0.x*A0f[(ln*2+0)*10 + o] + v0.y*A0f[(ln*2+1)*10 + o];

  auto stage8 = [&](int g, int sl){
    const char* g0 = P + (size_t)g*8192 + (size_t)ln*16;
    #pragma unroll
    for (int i = 0; i < 8; ++i)
      __builtin_amdgcn_global_load_lds((gas_t*)(const void*)(g0 + i*1024),
                                       (las_t*)(void*)(slot[sl] + i*1024), 16, 0, 0);
  };

  stage8(0, 0);
  stage8(1, 1);
  stage8(2, 2);
  const uint32_t swz = (uint32_t)(ln & 7) << 4;

  #pragma unroll 1
  for (int g = 0; g < 10; ++g){
    asm volatile("s_waitcnt vmcnt(16)" ::: "memory");
    {
      int gn = (g+3 > 9) ? 9 : (g+3);
      stage8(gn, (g+3) & 3);
    }
    #pragma unroll
    for (int o = 0; o < 10; ++o){
      float ot = __shfl_xor(u[o], 1);
      pk[o][ln>>1] = (ln & 1) ? packh2(ot, u[o]) : packh2(u[o], ot);
    }
    const char* sp = slot[g & 3] + (size_t)ln*128;
    uint4 wr[8];
    #pragma unroll
    for (int m = 0; m < 8; ++m) wr[m] = *(const uint4*)(sp + ((m*16) ^ swz));
    #pragma unroll
    for (int o = 0; o < 10; ++o){
      const uint4* lp = (const uint4*)pk[o];
      float acc = 0.f;
      #pragma unroll
      for (int m = 0; m < 8; ++m){
        uint4 q = lp[m];
        acc = fdot2f(wr[m].x, q.x, acc); acc = fdot2f(wr[m].y, q.y, acc);
        acc = fdot2f(wr[m].z, q.z, acc); acc = fdot2f(wr[m].w, q.w, acc);
      }
      u[o] += acc*INV;
    }
  }
  if (ln == 0){
    #pragma unroll
    for (int o = 0; o < 10; ++o) outp[(size_t)b*10 + o] = u[o];
  }
}

// ---------------- R5 MFMA scan (fallback) ----------------
__global__ __launch_bounds__(64, 1) void k_scan_m(
    const char* __restrict__ sL, const char* __restrict__ sR,
    float* __restrict__ Lout, float* __restrict__ Rout, int J, int n){
  __shared__ __align__(16) char lds[4*REC];
  const int ln = threadIdx.x;
  const int wg = blockIdx.x;
  const int dir = wg >> 2;
  const int colbase = (wg & 3)*32;
  const char* stream = dir ? sR : sL;
  float* Sout = dir ? Rout : Lout;
  const int outs = dir ? 8 : 0;
  const int b = colbase + (ln & 31);
  const int h4 = (ln >> 5)*4;
  const float INV = 1.f/256.f;

  f32x16 acc0, acc1;
  #pragma unroll
  for (int i = 0; i < 16; ++i){ acc0[i] = 0.f; acc1[i] = 0.f; }
  if (ln < 32) acc0[0] = 1.f;

  const char* gsrc = stream + (size_t)ln*16;
  stage17(gsrc,           lds);
  stage17(gsrc + REC,     lds + REC);
  stage17(gsrc + 2*REC,   lds + 2*REC);

  int pos = 0, jj = 0;
  for (int t = 0; t < n; ++t){
    asm volatile("s_waitcnt vmcnt(34)" ::: "memory");
    const char* slot = lds + (size_t)(t & 3)*REC;
    float2 vv = *(const float2*)(slot + 16384 + b*8);
    int tn = t + 3; if (tn > n-1) tn = n-1;
    stage17(gsrc + (size_t)tn*REC, lds + (size_t)(tn & 3)*REC);

    uint32_t px = pkf16(vv.x*INV, vv.x*INV);
    uint32_t py = pkf16(vv.y*INV, vv.y*INV);
    uint32_t bd0[8], bd1[8];
    MKBASE(acc0, bd0);
    MKBASE(acc1, bd1);

    if (pos == outs){
      int jdx = dir ? (J-1-jj) : jj;
      float* dst = Sout + ((size_t)jdx*128 + b)*64;
      #pragma unroll
      for (int q = 0; q < 4; ++q){
        float4 f0; f0.x = acc0[4*q]; f0.y = acc0[4*q+1]; f0.z = acc0[4*q+2]; f0.w = acc0[4*q+3];
        *(float4*)(dst + 8*q + h4) = f0;
        float4 f1; f1.x = acc1[4*q]; f1.y = acc1[4*q+1]; f1.z = acc1[4*q+2]; f1.w = acc1[4*q+3];
        *(float4*)(dst + 32 + 8*q + h4) = f1;
      }
      float alpha = 0.8f*(vv.x + vv.y);
      #pragma unroll
      for (int i = 0; i < 16; ++i){ acc0[i] *= alpha; acc1[i] *= alpha; }
    }

    MFMA8(slot);

    ++pos; if (pos == 9){ pos = 0; ++jj; }
  }
}

// ---------------- final layer R5 (fallback) ----------------
__global__ __launch_bounds__(64, 1) void k_final_m(
    const char* __restrict__ sF, const float* __restrict__ A0f,
    const float2* __restrict__ vF, float* __restrict__ outp){
  __shared__ __align__(16) char lds[4*REC];
  const int ln = threadIdx.x;
  const int wg = blockIdx.x;
  const int o = wg >> 2;
  const int b = (wg & 3)*32 + (ln & 31);
  const int h4 = (ln >> 5)*4;
  const float INV = 1.f/256.f;

  float2 v0 = vF[(size_t)b*81];
  f32x16 acc0, acc1;
  #pragma unroll
  for (int rg = 0; rg < 16; ++rg){
    int row0 = (rg & 3) + 8*(rg >> 2) + h4;
    acc0[rg] = v0.x*A0f[(row0*2+0)*10 + o] + v0.y*A0f[(row0*2+1)*10 + o];
    int row1 = row0 + 32;
    acc1[rg] = v0.x*A0f[(row1*2+0)*10 + o] + v0.y*A0f[(row1*2+1)*10 + o];
  }
  asm volatile("s_waitcnt vmcnt(0)" ::: "memory");

  const char* gsrc = sF + (size_t)ln*16;
  stage17(gsrc,         lds);
  stage17(gsrc + REC,   lds + REC);
  stage17(gsrc + 2*REC, lds + 2*REC);

  const int n = 80;
  for (int t = 0; t < n; ++t){
    asm volatile("s_waitcnt vmcnt(34)" ::: "memory");
    const char* slot = lds + (size_t)(t & 3)*REC;
    float2 vv = *(const float2*)(slot + 16384 + b*8);
    int tn = t + 3; if (tn > n-1) tn = n-1;
    stage17(gsrc + (size_t)tn*REC, lds + (size_t)(tn & 3)*REC);

    uint32_t px = pkf16(vv.x*INV, vv.x*INV);
    uint32_t py = pkf16(vv.y*INV, vv.y*INV);
    uint32_t bd0[8], bd1[8];
    MKBASE(acc0, bd0);
    MKBASE(acc1, bd1);
    MFMA8(slot);
  }
  if (ln < 32) outp[(size_t)b*10 + o] = acc0[0];
}

// ---------------- epilogue: 32b x 8 e-octants, grid (J,4) ----------------
template<bool EMB>
__global__ __launch_bounds__(256) void k_out(
    const float* __restrict__ Wout, const float* __restrict__ Lbuf,
    const float* __restrict__ Rbuf, const float2* __restrict__ v, int n,
    float* __restrict__ hout, float2* __restrict__ vF){
  __shared__ float tile[8][64][20];
  __shared__ float Lsh[32][65];
  const int j = blockIdx.x, bh = blockIdx.y;
  const int q = threadIdx.x >> 5, bl = threadIdx.x & 31;
  const int b = bh*32 + bl;
  for (int idx = threadIdx.x; idx < 32*64; idx += 256){
    int r = idx >> 6, d = idx & 63;
    Lsh[r][d] = Lbuf[((size_t)j*128 + bh*32 + r)*64 + d];
  }
  float Rr[8];
  {
    const float4* Rp = (const float4*)(Rbuf + ((size_t)j*128 + b)*64 + q*8);
    ((float4*)Rr)[0] = Rp[0];
    ((float4*)Rr)[1] = Rp[1];
  }
  float acc[18];
  #pragma unroll
  for (int k = 0; k < 18; ++k) acc[k] = 0.f;
  __syncthreads();
  for (int c = 0; c < 8; ++c){
    #pragma unroll
    for (int k = 0; k < 2; ++k){
      int pi = threadIdx.x*2 + k;
      int d8 = pi >> 6, e = pi & 63;
      const float* src = Wout + ((size_t)(j*64 + c*8 + d8)*64 + e)*18;
      float* dst = &tile[d8][e][0];
      #pragma unroll
      for (int mm = 0; mm < 18; ++mm) dst[mm] = src[mm];
    }
    __syncthreads();
    #pragma unroll 1
    for (int d8 = 0; d8 < 8; ++d8){
      float lw = Lsh[bl][c*8 + d8];
      #pragma unroll
      for (int i = 0; i < 8; ++i){
        int e = q*8 + i;
        float wbe = lw * Rr[i];
        const float* tp = &tile[d8][e][0];
        float4 t0 = *(const float4*)(tp);
        float4 t1 = *(const float4*)(tp+4);
        float4 t2 = *(const float4*)(tp+8);
        float4 t3 = *(const float4*)(tp+12);
        float2 t4 = *(const float2*)(tp+16);
        acc[0]  += wbe*t0.x; acc[1]  += wbe*t0.y; acc[2]  += wbe*t0.z; acc[3]  += wbe*t0.w;
        acc[4]  += wbe*t1.x; acc[5]  += wbe*t1.y; acc[6]  += wbe*t1.z; acc[7]  += wbe*t1.w;
        acc[8]  += wbe*t2.x; acc[9]  += wbe*t2.y; acc[10] += wbe*t2.z; acc[11] += wbe*t2.w;
        acc[12] += wbe*t3.x; acc[13] += wbe*t3.y; acc[14] += wbe*t3.z; acc[15] += wbe*t3.w;
        acc[16] += wbe*t4.x; acc[17] += wbe*t4.y;
      }
    }
    __syncthreads();
  }
  float* red = &tile[0][0][0];
  #pragma unroll
  for (int k = 0; k < 18; ++k) red[((size_t)q*32 + bl)*20 + k] = acc[k];
  __syncthreads();
  if (q == 0){
    float s[18];
    #pragma unroll
    for (int k = 0; k < 18; ++k){
      float t = 0.f;
      #pragma unroll
      for (int g = 0; g < 8; ++g) t += red[((size_t)g*32 + bl)*20 + k];
      s[k] = t;
    }
    float2 vo = v[(size_t)b*n + j*9];
    #pragma unroll
    for (int f = 0; f < 9; ++f){
      float val = vo.x*s[f] + vo.y*s[9+f];
      if (EMB){
        float s_, c_; sincosf(1.5707963267948966f*val, &s_, &c_);
        float2 e2; e2.x = c_; e2.y = s_;
        vF[(size_t)b*81 + j*9 + f] = e2;
      } else {
        hout[(size_t)b*729 + j*9 + f] = val;
      }
    }
  }
}

// ---------------- host ----------------
extern "C" void kernel_launch(void* const* d_in, const int* in_sizes, int n_in,
                              void* d_out, int out_size, void* d_ws, size_t ws_size,
                              hipStream_t stream){
  const float* x     = (const float*)d_in[0];
  const float* Wout0 = (const float*)d_in[1];
  const float* Wmid0 = (const float*)d_in[2];
  const float* Wout1 = (const float*)d_in[3];
  const float* Wmid1 = (const float*)d_in[4];
  const float* A0f   = (const float*)d_in[5];
  const float* WmidF = (const float*)d_in[6];
  float* outp = (float*)d_out;

  char* ws = (char*)d_ws;
  size_t off = 0;
  auto alloc = [&](size_t bytes) -> char* {
    char* p = ws + off;
    off = (off + bytes + 255) & ~(size_t)255;
    return p;
  };
  char* S0L = alloc((size_t)729*REC);
  char* S0R = alloc((size_t)729*REC);
  char* S1L = alloc((size_t)81*REC);
  char* S1R = alloc((size_t)81*REC);
  char* SF  = alloc((size_t)80*REC);
  float2* v0 = (float2*)alloc((size_t)128*729*8);
  float2* v1 = (float2*)alloc((size_t)128*81*8);
  float2* vF = (float2*)alloc((size_t)128*81*8);
  float* L0 = (float*)alloc((size_t)81*128*64*4);
  float* R0 = (float*)alloc((size_t)81*128*64*4);
  float* L1 = (float*)alloc((size_t)9*128*64*4);
  float* R1 = (float*)alloc((size_t)9*128*64*4);
  float* h1 = (float*)alloc((size_t)128*729*4);
  char* Tn1 = alloc((size_t)128*81*8192);
  char* Wn1 = alloc((size_t)128*81*8192);
  size_t need_r7 = off;
  char* Tn2 = alloc((size_t)128*9*8192);
  char* Wn2 = alloc((size_t)128*9*8192);
  char* GF  = alloc((size_t)128*10*8192);
  size_t need_full = off;
  bool full = (ws_size >= need_full);
  bool grp1 = (ws_size >= need_r7);
  (void)in_sizes; (void)n_in; (void)out_size;

  // streams
  k_build <<<1296,  256, 0, stream>>>(Wmid1, Wout1, S1L, 9, 81, 0);
  k_build <<<1296,  256, 0, stream>>>(Wmid1, Wout1, S1R, 9, 81, 1);
  k_buildF<<<1280,  256, 0, stream>>>(WmidF, SF);
  k_build<<<11664, 256, 0, stream>>>(Wmid0, Wout0, S0L, 81, 729, 0);
  k_build<<<11664, 256, 0, stream>>>(Wmid0, Wout0, S0R, 81, 729, 1);

  // layer 1
  k_embed<<<365, 256, 0, stream>>>(x, 81, 27, v0);
  if (grp1){
    k_prod <<<2592, 512, 0, stream>>>(S0L, S0R, v0, Tn1, Wn1, 81);
    k_gscan<<<256, 64, 0, stream>>>(Tn1, Wn1, v0, L0, R0, 81);
  } else {
    k_vrec <<<365, 256, 0, stream>>>(v0, S0L, 729, 729, 0);
    k_vrec <<<365, 256, 0, stream>>>(v0, S0R, 729, 729, 1);
    k_scan_m<<<8, 64, 0, stream>>>(S0L, S0R, L0, R0, 81, 729);
  }
  k_out<false><<<dim3(81,4), 256, 0, stream>>>(Wout0, L0, R0, v0, 729, h1, (float2*)nullptr);

  // layer 2
  k_embed<<<41, 256, 0, stream>>>(h1, 27, 9, v1);
  if (full){
    k_prod <<<288, 512, 0, stream>>>(S1L, S1R, v1, Tn2, Wn2, 9);
    k_gscan<<<256, 64, 0, stream>>>(Tn2, Wn2, v1, L1, R1, 9);
  } else {
    k_vrec <<<41, 256, 0, stream>>>(v1, S1L, 81, 81, 0);
    k_vrec <<<41, 256, 0, stream>>>(v1, S1R, 81, 81, 1);
    k_scan_m<<<8, 64, 0, stream>>>(S1L, S1R, L1, R1, 9, 81);
  }
  k_out<true><<<dim3(9,4), 256, 0, stream>>>(Wout1, L1, R1, v1, 81, (float*)nullptr, vF);

  // final layer
  if (full){
    k_prodF<<<160, 512, 0, stream>>>(SF, vF, GF);
    k_fscan<<<128, 64, 0, stream>>>(GF, A0f, vF, outp);
  } else {
    k_vrec <<<40, 256, 0, stream>>>(vF, SF, 80, 81, 2);
    k_final_m<<<40, 64, 0, stream>>>(SF, A0f, vF, outp);
  }
}

// Round 15
// 470.889 us; speedup vs baseline: 1.1037x; 1.0674x over previous
//
#include <hip/hip_runtime.h>
#include <cstdint>
#include <cstddef>

// MLSMPO on MI355X — R15: R14 + 3-slot LDS (48KB) k_prod/k_prodF.
// 144KB LDS forced 1 block/CU (2 waves/SIMD) -> latency-bound. 3-slot rotating
// buffer with counted vmcnt(2) + raw s_barrier (R10's verified schedule) gives
// 3 blocks/CU = 6 waves/SIMD for cross-block overlap. permlane MKBASE kept.

typedef float    f32x16 __attribute__((ext_vector_type(16)));
typedef _Float16 f16x8  __attribute__((ext_vector_type(8)));
typedef __fp16   fp16x2 __attribute__((ext_vector_type(2)));
typedef _Float16 h2_t   __attribute__((ext_vector_type(2)));
typedef unsigned int uint32x2_t __attribute__((ext_vector_type(2)));
typedef const void __attribute__((address_space(1))) gas_t;
typedef void       __attribute__((address_space(3))) las_t;

union U16  { uint4 u; f16x8 h; };
union B16u { uint32_t u[4]; f16x8 h; };
union H2U  { fp16x2 h; uint32_t u; };

__device__ __forceinline__ uint32_t pkf16(float a, float b){   // RTZ (hot path only)
  H2U z; z.h = __builtin_amdgcn_cvt_pkrtz(a, b); return z.u;
}
__device__ __forceinline__ uint32_t pkmul(uint32_t a, uint32_t b){
  H2U x, y, r; x.u = a; y.u = b;
  r.h = x.h * y.h; return r.u;
}
__device__ __forceinline__ uint32_t packh2(float a, float b){  // RTNE
  union { _Float16 h[2]; uint32_t u; } z;
  z.h[0] = (_Float16)a; z.h[1] = (_Float16)b; return z.u;
}
__device__ __forceinline__ float fdot2f(uint32_t wa, uint32_t wb, float acc){
  union U { uint32_t u; h2_t h; };
  U a, b; a.u = wa; b.u = wb;
  return __builtin_amdgcn_fdot2(a.h, b.h, acc, false);
}

#define REC 17408   // bytes per stream step: 16KB A-frags + 1KB v-record

// ---------------- stream builders (verified R5) ----------------
__global__ void k_build(const float* __restrict__ Wmid, const float* __restrict__ Wout,
                        char* __restrict__ S, int J, int n, int dirR){
  int tid = blockIdx.x*256 + threadIdx.x;
  if (tid >= n*4096) return;
  int gt = tid >> 12, r = tid & 4095;
  int f = r >> 8, ln = (r >> 2) & 63, dw = r & 3;
  int s = f >> 1, m = f & 1;
  int row = m*32 + (ln & 31);
  int kb = s*16 + (ln >> 5)*8 + dw*2;
  int p = kb >> 6, q = kb & 63;
  int jj = gt/9, pos = gt - jj*9;
  int j = dirR ? (J-1-jj) : jj;
  int outs = dirR ? 8 : 0;
  float w[2];
  #pragma unroll
  for (int k2 = 0; k2 < 2; ++k2){
    int qq = q + k2;
    int d = dirR ? row : qq;
    int e = dirR ? qq : row;
    float val;
    if (pos == outs){
      const float* src = Wout + ((((size_t)j*64 + d)*64 + e)*2 + p)*9;
      val = 0.f;
      #pragma unroll
      for (int ff = 0; ff < 9; ++ff) val += src[ff];
      if (d == e) val -= 0.8f;
    } else {
      int mi = dirR ? (7 - pos) : (pos - 1);
      val = Wmid[((((size_t)j*8 + mi)*64 + d)*64 + e)*2 + p];
    }
    w[k2] = val;
  }
  uint32_t* S32 = (uint32_t*)(S + (size_t)gt*REC);
  S32[f*256 + ln*4 + dw] = packh2(w[0]*256.f, w[1]*256.f);
}

__global__ void k_buildF(const float* __restrict__ Wm, char* __restrict__ S){
  int tid = blockIdx.x*256 + threadIdx.x;
  if (tid >= 80*4096) return;
  int gt = tid >> 12, r = tid & 4095;
  int f = r >> 8, ln = (r >> 2) & 63, dw = r & 3;
  int s = f >> 1, m = f & 1;
  int row = m*32 + (ln & 31);
  int kb = s*16 + (ln >> 5)*8 + dw*2;
  int p = kb >> 6, q = kb & 63;
  float w[2];
  #pragma unroll
  for (int k2 = 0; k2 < 2; ++k2){
    int d = q + k2, e = row;
    w[k2] = Wm[(((size_t)gt*64 + d)*64 + e)*2 + p];
  }
  uint32_t* S32 = (uint32_t*)(S + (size_t)gt*REC);
  S32[f*256 + ln*4 + dw] = packh2(w[0]*256.f, w[1]*256.f);
}

__global__ void k_vrec(const float2* __restrict__ v, char* __restrict__ S,
                       int n, int nv, int mode){
  int tid = blockIdx.x*256 + threadIdx.x;
  if (tid >= n*128) return;
  int gt = tid >> 7, b = tid & 127;
  int site = (mode == 0) ? gt : (mode == 1) ? (n-1-gt) : (gt+1);
  *(float2*)(S + (size_t)gt*REC + 16384 + b*8) = v[(size_t)b*nv + site];
}

// ---------------- patch embed ----------------
__global__ void k_embed(const float* __restrict__ img, int Wd, int PG,
                        float2* __restrict__ outv){
  int tid = blockIdx.x*256 + threadIdx.x;
  int NP = PG*PG;
  if (tid >= 128*NP) return;
  int b = tid / NP, s = tid - b*NP;
  int pi = s / PG, pj = s - pi*PG;
  const float* base = img + (size_t)b*Wd*Wd + (size_t)(3*pi)*Wd + 3*pj;
  float cs = 0.f, sn = 0.f;
  #pragma unroll
  for (int r = 0; r < 3; ++r){
    #pragma unroll
    for (int c = 0; c < 3; ++c){
      float x = base[r*Wd + c];
      float s_, c_; sincosf(1.5707963267948966f*x, &s_, &c_);
      cs += c_; sn += s_;
    }
  }
  cs *= (1.f/9.f); sn *= (1.f/9.f);
  float rn = rsqrtf(cs*cs + sn*sn);
  float2 v; v.x = cs*rn; v.y = sn*rn;
  outv[tid] = v;
}

// ---------------- shared MFMA helpers ----------------
__device__ __forceinline__ void stage17(const char* g, char* l){
  #pragma unroll
  for (int i = 0; i < 17; ++i)
    __builtin_amdgcn_global_load_lds((gas_t*)(const void*)(g + i*1024),
                                     (las_t*)(void*)(l + i*1024), 16, 0, 0);
}

// D(f32x16 tile) -> 8 B-frag base dwords via permlane32_swap (VALU, no LDS).
// swap(A,B): A.hi <-> B.lo; returns {newA={A.lo,B.lo}, newB={A.hi,B.hi}}.
#define MKBASE(acc, bd) do { \
  uint32_t P0 = pkf16(acc[0],acc[1]),  P1 = pkf16(acc[2],acc[3]); \
  uint32_t P2 = pkf16(acc[4],acc[5]),  P3 = pkf16(acc[6],acc[7]); \
  { uint32x2_t r_ = __builtin_amdgcn_permlane32_swap(P0, P2, false, false); \
    bd[0] = r_[0]; bd[2] = r_[1]; } \
  { uint32x2_t r_ = __builtin_amdgcn_permlane32_swap(P1, P3, false, false); \
    bd[1] = r_[0]; bd[3] = r_[1]; } \
  uint32_t R0 = pkf16(acc[8],acc[9]),   R1 = pkf16(acc[10],acc[11]); \
  uint32_t R2 = pkf16(acc[12],acc[13]), R3 = pkf16(acc[14],acc[15]); \
  { uint32x2_t r_ = __builtin_amdgcn_permlane32_swap(R0, R2, false, false); \
    bd[4] = r_[0]; bd[6] = r_[1]; } \
  { uint32x2_t r_ = __builtin_amdgcn_permlane32_swap(R1, R3, false, false); \
    bd[5] = r_[0]; bd[7] = r_[1]; } \
} while(0)

#define MFMA8(slotp) do { \
  const uint4* fr_ = (const uint4*)(slotp); \
  _Pragma("unroll") \
  for (int s_ = 0; s_ < 8; ++s_){ \
    const int sl_ = s_ & 3; \
    const uint32_t* bb_ = (sl_ < 2) ? bd0 : bd1; \
    const int off_ = (sl_ & 1)*4; \
    const uint32_t scl_ = (s_ < 4) ? px : py; \
    B16u bs_; \
    _Pragma("unroll") \
    for (int dw_ = 0; dw_ < 4; ++dw_) bs_.u[dw_] = pkmul(bb_[off_+dw_], scl_); \
    U16 fa0_, fa1_; \
    fa0_.u = fr_[(2*s_)*64 + ln]; \
    fa1_.u = fr_[(2*s_+1)*64 + ln]; \
    acc0 = __builtin_amdgcn_mfma_f32_32x32x16_f16(fa0_.h, bs_.h, acc0, 0, 0, 0); \
    acc1 = __builtin_amdgcn_mfma_f32_32x32x16_f16(fa1_.h, bs_.h, acc1, 0, 0, 0); \
  } \
} while(0)

// 4-tile MFMA body shared by k_prod/k_prodF
#define PROD_SLOOP(buf) do { \
  const uint4* fr = (const uint4*)(buf); \
  _Pragma("unroll") \
  for (int s = 0; s < 8; ++s){ \
    const int sl = s & 3; \
    const uint32_t scl = (s < 4) ? px : py; \
    const int off = (sl & 1)*4; \
    U16 f0, f1; \
    f0.u = fr[(2*s)*64 + ln]; \
    f1.u = fr[(2*s+1)*64 + ln]; \
    { \
      const uint32_t* bb = (sl < 2) ? bl0 : bh0; \
      B16u bs; \
      _Pragma("unroll") \
      for (int dw = 0; dw < 4; ++dw) bs.u[dw] = pkmul(bb[off+dw], scl); \
      a00 = __builtin_amdgcn_mfma_f32_32x32x16_f16(f0.h, bs.h, a00, 0, 0, 0); \
      a10 = __builtin_amdgcn_mfma_f32_32x32x16_f16(f1.h, bs.h, a10, 0, 0, 0); \
    } \
    { \
      const uint32_t* bb = (sl < 2) ? bl1 : bh1; \
      B16u bs; \
      _Pragma("unroll") \
      for (int dw = 0; dw < 4; ++dw) bs.u[dw] = pkmul(bb[off+dw], scl); \
      a01 = __builtin_amdgcn_mfma_f32_32x32x16_f16(f0.h, bs.h, a01, 0, 0, 0); \
      a11 = __builtin_amdgcn_mfma_f32_32x32x16_f16(f1.h, bs.h, a11, 0, 0, 0); \
    } \
  } \
} while(0)

#define PROD_INIT_I() do { \
  _Pragma("unroll") \
  for (int i = 0; i < 16; ++i){ a00[i]=0.f; a01[i]=0.f; a10[i]=0.f; a11[i]=0.f; } \
  if (((i32 >> 2) & 1) == h){ \
    int rr0 = (i32 & 3) | ((i32 >> 3) << 2); \
    _Pragma("unroll") \
    for (int rr = 0; rr < 16; ++rr) \
      if (rr == rr0){ a00[rr] = 1.f; a11[rr] = 1.f; } \
  } \
} while(0)

#define PROD_WRITEOUT(ob, diagc) do { \
  _Pragma("unroll") \
  for (int x = 0; x < 2; ++x){ \
    _Pragma("unroll") \
    for (int y = 0; y < 2; ++y){ \
      const f32x16& A = (x==0) ? (y==0 ? a00 : a01) : (y==0 ? a10 : a11); \
      int C = y*32 + i32; \
      _Pragma("unroll") \
      for (int r = 0; r < 16; ++r){ \
        int R = x*32 + (r & 3) + 8*(r >> 2) + 4*h; \
        float val = (A[r] - ((R == C) ? (diagc) : 0.f))*256.f; \
        float oth = __shfl_xor(val, 1); \
        if (!(ln & 1)){ \
          uint32_t dwv = packh2(val, oth); \
          *(uint32_t*)((ob) + R*128 + ((C*2) ^ ((R & 7) << 4))) = dwv; \
        } \
      } \
    } \
  } \
} while(0)

// one chain step: repack state, optional t==0 alpha-scale, 32 MFMA
#define PROD_STEP(t, doalpha, bufp) do { \
  uint32_t px = pkf16(vv[t].x*INV, vv[t].x*INV); \
  uint32_t py = pkf16(vv[t].y*INV, vv[t].y*INV); \
  uint32_t bl0[8], bh0[8], bl1[8], bh1[8]; \
  MKBASE(a00, bl0); MKBASE(a10, bh0); \
  MKBASE(a01, bl1); MKBASE(a11, bh1); \
  if (doalpha){ \
    _Pragma("unroll") \
    for (int i = 0; i < 16; ++i){ \
      a00[i] *= alphaC; a01[i] *= alphaC; a10[i] *= alphaC; a11[i] *= alphaC; \
    } \
  } \
  PROD_SLOOP(bufp); \
} while(0)

// ---------------- group-product production (layers) ----------------
// XCD-remapped grid; 3-slot rotating LDS (48KB -> 3 blocks/CU), per step:
// vmcnt(2) -> raw s_barrier -> stage(t+2, clamped) -> compute(t).
__global__ __launch_bounds__(512, 1) void k_prod(
    const char* __restrict__ sL, const char* __restrict__ sR,
    const float2* __restrict__ v, char* __restrict__ Tn, char* __restrict__ Wn,
    int J){
  __shared__ __align__(16) char lds[3][16384];
  const int ln = threadIdx.x & 63, w = threadIdx.x >> 6;
  const int wid = (blockIdx.x & 7)*(J*4) + (blockIdx.x >> 3);
  const int bg = wid & 15;
  const int pair = wid >> 4;
  const int dir = pair & 1, j = pair >> 1;
  const int b = bg*8 + w;
  const int h = ln >> 5, i32 = ln & 31;
  const float INV = 1.f/256.f;
  const char* stream = dir ? sR : sL;
  const int n = J*9;

  float2 vv[9];
  {
    const float2* vbase = v + (size_t)b*n + j*9;
    #pragma unroll
    for (int t = 0; t < 9; ++t) vv[t] = vbase[dir ? (9 - t) : t];
  }
  const float alphaC = (dir && j == J-1) ? 1.0f : 0.8f*(vv[0].x + vv[0].y);
  if (dir && j == J-1){ vv[0].x = 0.f; vv[0].y = 0.f; }

  auto gtf = [&](int t) -> int {
    int g = dir ? ((J-2-j)*9 + 8 + t) : (j*9 + t);
    return g < 0 ? 0 : g;
  };
  auto stage = [&](int t, int sl){
    const char* g0 = stream + (size_t)gtf(t)*REC + (size_t)(2*w)*1024 + (size_t)ln*16;
    __builtin_amdgcn_global_load_lds((gas_t*)(const void*)g0,
                                     (las_t*)(void*)(lds[sl] + 2*w*1024), 16, 0, 0);
    __builtin_amdgcn_global_load_lds((gas_t*)(const void*)(g0 + 1024),
                                     (las_t*)(void*)(lds[sl] + (2*w+1)*1024), 16, 0, 0);
  };

  f32x16 a00, a01, a10, a11;
  PROD_INIT_I();

  stage(0, 0);
  stage(1, 1);
  #pragma unroll
  for (int t = 0; t < 9; ++t){
    asm volatile("s_waitcnt vmcnt(2)" ::: "memory");
    __builtin_amdgcn_s_barrier();
    {
      int tn = (t+2 > 8) ? 8 : (t+2);
      stage(tn, (t+2) % 3);
    }
    if (t == 0){ PROD_STEP(0, true, lds[0]); }
    else       { PROD_STEP(t, false, lds[t % 3]); }
  }

  char* ob = (dir ? Wn : Tn) + ((size_t)b*J + j)*8192;
  PROD_WRITEOUT(ob, alphaC);
}

// ---------------- final-layer group products: G_g^T, 10 groups x 8 mids ----
__global__ __launch_bounds__(512, 1) void k_prodF(
    const char* __restrict__ sF, const float2* __restrict__ vF,
    char* __restrict__ GF){
  __shared__ __align__(16) char lds[3][16384];
  const int ln = threadIdx.x & 63, w = threadIdx.x >> 6;
  const int wid = (blockIdx.x & 7)*20 + (blockIdx.x >> 3);
  const int bg = wid & 15, g = wid >> 4;
  const int b = bg*8 + w;
  const int h = ln >> 5, i32 = ln & 31;
  const float INV = 1.f/256.f;
  const float alphaC = 1.0f;   // unused (doalpha=false); scope for PROD_STEP

  float2 vv[8];
  {
    const float2* vbase = vF + (size_t)b*81 + g*8 + 1;
    #pragma unroll
    for (int t = 0; t < 8; ++t) vv[t] = vbase[t];
  }
  auto stage = [&](int t, int sl){
    const char* g0 = sF + (size_t)(g*8 + t)*REC + (size_t)(2*w)*1024 + (size_t)ln*16;
    __builtin_amdgcn_global_load_lds((gas_t*)(const void*)g0,
                                     (las_t*)(void*)(lds[sl] + 2*w*1024), 16, 0, 0);
    __builtin_amdgcn_global_load_lds((gas_t*)(const void*)(g0 + 1024),
                                     (las_t*)(void*)(lds[sl] + (2*w+1)*1024), 16, 0, 0);
  };

  f32x16 a00, a01, a10, a11;
  PROD_INIT_I();

  stage(0, 0);
  stage(1, 1);
  #pragma unroll
  for (int t = 0; t < 8; ++t){
    asm volatile("s_waitcnt vmcnt(2)" ::: "memory");
    __builtin_amdgcn_s_barrier();
    {
      int tn = (t+2 > 7) ? 7 : (t+2);
      stage(tn, (t+2) % 3);
    }
    PROD_STEP(t, false, lds[t % 3]);
  }

  char* ob = GF + ((size_t)b*10 + g)*8192;
  PROD_WRITEOUT(ob, 1.0f);
}

// ---------------- group-level env scans (layers), depth-3 ----------------
__global__ __launch_bounds__(64, 1) void k_gscan(
    const char* __restrict__ Tn, const char* __restrict__ Wn,
    const float2* __restrict__ v,
    float* __restrict__ Lout, float* __restrict__ Rout, int J){
  __shared__ __align__(16) char slot[4][8192];
  __shared__ __align__(16) float2 vvs[81];
  __shared__ __align__(16) uint32_t pk32[32];
  const int ln = threadIdx.x;
  const int dir = blockIdx.x >> 7;
  const int b = blockIdx.x & 127;
  const float INV = 1.f/256.f;
  const char* P = (dir ? Wn : Tn) + (size_t)b*J*8192;

  for (int g = ln; g < J; g += 64) vvs[g] = v[(size_t)b*(J*9) + (size_t)g*9];

  auto JD = [&](int g){ return dir ? (J-1-g) : g; };
  auto stage8 = [&](int jx, int sl){
    const char* g0 = P + (size_t)jx*8192 + (size_t)ln*16;
    #pragma unroll
    for (int i = 0; i < 8; ++i)
      __builtin_amdgcn_global_load_lds((gas_t*)(const void*)(g0 + i*1024),
                                       (las_t*)(void*)(slot[sl] + i*1024), 16, 0, 0);
  };

  stage8(JD(0), 0);
  stage8(JD(1 < J-1 ? 1 : J-1), 1);
  stage8(JD(2 < J-1 ? 2 : J-1), 2);

  float st = (ln == 0) ? 1.f : 0.f;
  const uint32_t swz = (uint32_t)(ln & 7) << 4;

  #pragma unroll 1
  for (int g = 0; g < J; ++g){
    const int j = JD(g);
    asm volatile("s_waitcnt vmcnt(16)" ::: "memory");
    if (!dir) Lout[((size_t)j*128 + b)*64 + ln] = st;
    {
      int gn = (g+3 > J-1) ? (J-1) : (g+3);
      stage8(JD(gn), (g+3) & 3);
    }

    float c;
    if (dir) c = (j < J-1) ? 0.8f*(vvs[j+1].x + vvs[j+1].y) : 1.0f;
    else     c = 0.8f*(vvs[j].x + vvs[j].y);

    {
      float o = __shfl_xor(st, 1);
      pk32[ln>>1] = (ln & 1) ? packh2(o, st) : packh2(st, o);
    }
    const char* sp = slot[g & 3] + (size_t)ln*128;
    const uint4* lp = (const uint4*)pk32;
    float acc = 0.f;
    #pragma unroll
    for (int m = 0; m < 8; ++m){
      uint4 q = lp[m];
      uint4 ww = *(const uint4*)(sp + ((m*16) ^ swz));
      acc = fdot2f(ww.x, q.x, acc); acc = fdot2f(ww.y, q.y, acc);
      acc = fdot2f(ww.z, q.z, acc); acc = fdot2f(ww.w, q.w, acc);
    }
    st = c*st + acc*INV;
    if (dir) Rout[((size_t)j*128 + b)*64 + ln] = st;
  }
}

// ---------------- final-layer group scan, depth-3 ----------
__global__ __launch_bounds__(64, 1) void k_fscan(
    const char* __restrict__ GF, const float* __restrict__ A0f,
    const float2* __restrict__ vF, float* __restrict__ outp){
  __shared__ __align__(16) char slot[4][8192];
  __shared__ __align__(16) uint32_t pk[10][32];
  const int ln = threadIdx.x;
  const int b = blockIdx.x;
  const float INV = 1.f/256.f;
  const char* P = GF + (size_t)b*10*8192;

  float2 v0 = vF[(size_t)b*81];
  float u[10];
  #pragma unroll
  for (int o = 0; o < 10; ++o)
    u[o] = v0.x*A0f[(ln*2+0)*10 + o] + v0.y*A0f[(ln*2+1)*10 + o];

  auto stage8 = [&](int g, int sl){
    const char* g0 = P + (size_t)g*8192 + (size_t)ln*16;
    #pragma unroll
    for (int i = 0; i < 8; ++i)
      __builtin_amdgcn_global_load_lds((gas_t*)(const void*)(g0 + i*1024),
                                       (las_t*)(void*)(slot[sl] + i*1024), 16, 0, 0);
  };

  stage8(0, 0);
  stage8(1, 1);
  stage8(2, 2);
  const uint32_t swz = (uint32_t)(ln & 7) << 4;

  #pragma unroll 1
  for (int g = 0; g < 10; ++g){
    asm volatile("s_waitcnt vmcnt(16)" ::: "memory");
    {
      int gn = (g+3 > 9) ? 9 : (g+3);
      stage8(gn, (g+3) & 3);
    }
    #pragma unroll
    for (int o = 0; o < 10; ++o){
      float ot = __shfl_xor(u[o], 1);
      pk[o][ln>>1] = (ln & 1) ? packh2(ot, u[o]) : packh2(u[o], ot);
    }
    const char* sp = slot[g & 3] + (size_t)ln*128;
    uint4 wr[8];
    #pragma unroll
    for (int m = 0; m < 8; ++m) wr[m] = *(const uint4*)(sp + ((m*16) ^ swz));
    #pragma unroll
    for (int o = 0; o < 10; ++o){
      const uint4* lp = (const uint4*)pk[o];
      float acc = 0.f;
      #pragma unroll
      for (int m = 0; m < 8; ++m){
        uint4 q = lp[m];
        acc = fdot2f(wr[m].x, q.x, acc); acc = fdot2f(wr[m].y, q.y, acc);
        acc = fdot2f(wr[m].z, q.z, acc); acc = fdot2f(wr[m].w, q.w, acc);
      }
      u[o] += acc*INV;
    }
  }
  if (ln == 0){
    #pragma unroll
    for (int o = 0; o < 10; ++o) outp[(size_t)b*10 + o] = u[o];
  }
}

// ---------------- R5 MFMA scan (fallback) ----------------
__global__ __launch_bounds__(64, 1) void k_scan_m(
    const char* __restrict__ sL, const char* __restrict__ sR,
    float* __restrict__ Lout, float* __restrict__ Rout, int J, int n){
  __shared__ __align__(16) char lds[4*REC];
  const int ln = threadIdx.x;
  const int wg = blockIdx.x;
  const int dir = wg >> 2;
  const int colbase = (wg & 3)*32;
  const char* stream = dir ? sR : sL;
  float* Sout = dir ? Rout : Lout;
  const int outs = dir ? 8 : 0;
  const int b = colbase + (ln & 31);
  const int h4 = (ln >> 5)*4;
  const float INV = 1.f/256.f;

  f32x16 acc0, acc1;
  #pragma unroll
  for (int i = 0; i < 16; ++i){ acc0[i] = 0.f; acc1[i] = 0.f; }
  if (ln < 32) acc0[0] = 1.f;

  const char* gsrc = stream + (size_t)ln*16;
  stage17(gsrc,           lds);
  stage17(gsrc + REC,     lds + REC);
  stage17(gsrc + 2*REC,   lds + 2*REC);

  int pos = 0, jj = 0;
  for (int t = 0; t < n; ++t){
    asm volatile("s_waitcnt vmcnt(34)" ::: "memory");
    const char* slot = lds + (size_t)(t & 3)*REC;
    float2 vv = *(const float2*)(slot + 16384 + b*8);
    int tn = t + 3; if (tn > n-1) tn = n-1;
    stage17(gsrc + (size_t)tn*REC, lds + (size_t)(tn & 3)*REC);

    uint32_t px = pkf16(vv.x*INV, vv.x*INV);
    uint32_t py = pkf16(vv.y*INV, vv.y*INV);
    uint32_t bd0[8], bd1[8];
    MKBASE(acc0, bd0);
    MKBASE(acc1, bd1);

    if (pos == outs){
      int jdx = dir ? (J-1-jj) : jj;
      float* dst = Sout + ((size_t)jdx*128 + b)*64;
      #pragma unroll
      for (int q = 0; q < 4; ++q){
        float4 f0; f0.x = acc0[4*q]; f0.y = acc0[4*q+1]; f0.z = acc0[4*q+2]; f0.w = acc0[4*q+3];
        *(float4*)(dst + 8*q + h4) = f0;
        float4 f1; f1.x = acc1[4*q]; f1.y = acc1[4*q+1]; f1.z = acc1[4*q+2]; f1.w = acc1[4*q+3];
        *(float4*)(dst + 32 + 8*q + h4) = f1;
      }
      float alpha = 0.8f*(vv.x + vv.y);
      #pragma unroll
      for (int i = 0; i < 16; ++i){ acc0[i] *= alpha; acc1[i] *= alpha; }
    }

    MFMA8(slot);

    ++pos; if (pos == 9){ pos = 0; ++jj; }
  }
}

// ---------------- final layer R5 (fallback) ----------------
__global__ __launch_bounds__(64, 1) void k_final_m(
    const char* __restrict__ sF, const float* __restrict__ A0f,
    const float2* __restrict__ vF, float* __restrict__ outp){
  __shared__ __align__(16) char lds[4*REC];
  const int ln = threadIdx.x;
  const int wg = blockIdx.x;
  const int o = wg >> 2;
  const int b = (wg & 3)*32 + (ln & 31);
  const int h4 = (ln >> 5)*4;
  const float INV = 1.f/256.f;

  float2 v0 = vF[(size_t)b*81];
  f32x16 acc0, acc1;
  #pragma unroll
  for (int rg = 0; rg < 16; ++rg){
    int row0 = (rg & 3) + 8*(rg >> 2) + h4;
    acc0[rg] = v0.x*A0f[(row0*2+0)*10 + o] + v0.y*A0f[(row0*2+1)*10 + o];
    int row1 = row0 + 32;
    acc1[rg] = v0.x*A0f[(row1*2+0)*10 + o] + v0.y*A0f[(row1*2+1)*10 + o];
  }
  asm volatile("s_waitcnt vmcnt(0)" ::: "memory");

  const char* gsrc = sF + (size_t)ln*16;
  stage17(gsrc,         lds);
  stage17(gsrc + REC,   lds + REC);
  stage17(gsrc + 2*REC, lds + 2*REC);

  const int n = 80;
  for (int t = 0; t < n; ++t){
    asm volatile("s_waitcnt vmcnt(34)" ::: "memory");
    const char* slot = lds + (size_t)(t & 3)*REC;
    float2 vv = *(const float2*)(slot + 16384 + b*8);
    int tn = t + 3; if (tn > n-1) tn = n-1;
    stage17(gsrc + (size_t)tn*REC, lds + (size_t)(tn & 3)*REC);

    uint32_t px = pkf16(vv.x*INV, vv.x*INV);
    uint32_t py = pkf16(vv.y*INV, vv.y*INV);
    uint32_t bd0[8], bd1[8];
    MKBASE(acc0, bd0);
    MKBASE(acc1, bd1);
    MFMA8(slot);
  }
  if (ln < 32) outp[(size_t)b*10 + o] = acc0[0];
}

// ---------------- epilogue: 32b x 8 e-octants, grid (J,4) ----------------
template<bool EMB>
__global__ __launch_bounds__(256) void k_out(
    const float* __restrict__ Wout, const float* __restrict__ Lbuf,
    const float* __restrict__ Rbuf, const float2* __restrict__ v, int n,
    float* __restrict__ hout, float2* __restrict__ vF){
  __shared__ float tile[8][64][20];
  __shared__ float Lsh[32][65];
  const int j = blockIdx.x, bh = blockIdx.y;
  const int q = threadIdx.x >> 5, bl = threadIdx.x & 31;
  const int b = bh*32 + bl;
  for (int idx = threadIdx.x; idx < 32*64; idx += 256){
    int r = idx >> 6, d = idx & 63;
    Lsh[r][d] = Lbuf[((size_t)j*128 + bh*32 + r)*64 + d];
  }
  float Rr[8];
  {
    const float4* Rp = (const float4*)(Rbuf + ((size_t)j*128 + b)*64 + q*8);
    ((float4*)Rr)[0] = Rp[0];
    ((float4*)Rr)[1] = Rp[1];
  }
  float acc[18];
  #pragma unroll
  for (int k = 0; k < 18; ++k) acc[k] = 0.f;
  __syncthreads();
  for (int c = 0; c < 8; ++c){
    #pragma unroll
    for (int k = 0; k < 2; ++k){
      int pi = threadIdx.x*2 + k;
      int d8 = pi >> 6, e = pi & 63;
      const float* src = Wout + ((size_t)(j*64 + c*8 + d8)*64 + e)*18;
      float* dst = &tile[d8][e][0];
      #pragma unroll
      for (int mm = 0; mm < 18; ++mm) dst[mm] = src[mm];
    }
    __syncthreads();
    #pragma unroll 1
    for (int d8 = 0; d8 < 8; ++d8){
      float lw = Lsh[bl][c*8 + d8];
      #pragma unroll
      for (int i = 0; i < 8; ++i){
        int e = q*8 + i;
        float wbe = lw * Rr[i];
        const float* tp = &tile[d8][e][0];
        float4 t0 = *(const float4*)(tp);
        float4 t1 = *(const float4*)(tp+4);
        float4 t2 = *(const float4*)(tp+8);
        float4 t3 = *(const float4*)(tp+12);
        float2 t4 = *(const float2*)(tp+16);
        acc[0]  += wbe*t0.x; acc[1]  += wbe*t0.y; acc[2]  += wbe*t0.z; acc[3]  += wbe*t0.w;
        acc[4]  += wbe*t1.x; acc[5]  += wbe*t1.y; acc[6]  += wbe*t1.z; acc[7]  += wbe*t1.w;
        acc[8]  += wbe*t2.x; acc[9]  += wbe*t2.y; acc[10] += wbe*t2.z; acc[11] += wbe*t2.w;
        acc[12] += wbe*t3.x; acc[13] += wbe*t3.y; acc[14] += wbe*t3.z; acc[15] += wbe*t3.w;
        acc[16] += wbe*t4.x; acc[17] += wbe*t4.y;
      }
    }
    __syncthreads();
  }
  float* red = &tile[0][0][0];
  #pragma unroll
  for (int k = 0; k < 18; ++k) red[((size_t)q*32 + bl)*20 + k] = acc[k];
  __syncthreads();
  if (q == 0){
    float s[18];
    #pragma unroll
    for (int k = 0; k < 18; ++k){
      float t = 0.f;
      #pragma unroll
      for (int g = 0; g < 8; ++g) t += red[((size_t)g*32 + bl)*20 + k];
      s[k] = t;
    }
    float2 vo = v[(size_t)b*n + j*9];
    #pragma unroll
    for (int f = 0; f < 9; ++f){
      float val = vo.x*s[f] + vo.y*s[9+f];
      if (EMB){
        float s_, c_; sincosf(1.5707963267948966f*val, &s_, &c_);
        float2 e2; e2.x = c_; e2.y = s_;
        vF[(size_t)b*81 + j*9 + f] = e2;
      } else {
        hout[(size_t)b*729 + j*9 + f] = val;
      }
    }
  }
}

// ---------------- host ----------------
extern "C" void kernel_launch(void* const* d_in, const int* in_sizes, int n_in,
                              void* d_out, int out_size, void* d_ws, size_t ws_size,
                              hipStream_t stream){
  const float* x     = (const float*)d_in[0];
  const float* Wout0 = (const float*)d_in[1];
  const float* Wmid0 = (const float*)d_in[2];
  const float* Wout1 = (const float*)d_in[3];
  const float* Wmid1 = (const float*)d_in[4];
  const float* A0f   = (const float*)d_in[5];
  const float* WmidF = (const float*)d_in[6];
  float* outp = (float*)d_out;

  char* ws = (char*)d_ws;
  size_t off = 0;
  auto alloc = [&](size_t bytes) -> char* {
    char* p = ws + off;
    off = (off + bytes + 255) & ~(size_t)255;
    return p;
  };
  char* S0L = alloc((size_t)729*REC);
  char* S0R = alloc((size_t)729*REC);
  char* S1L = alloc((size_t)81*REC);
  char* S1R = alloc((size_t)81*REC);
  char* SF  = alloc((size_t)80*REC);
  float2* v0 = (float2*)alloc((size_t)128*729*8);
  float2* v1 = (float2*)alloc((size_t)128*81*8);
  float2* vF = (float2*)alloc((size_t)128*81*8);
  float* L0 = (float*)alloc((size_t)81*128*64*4);
  float* R0 = (float*)alloc((size_t)81*128*64*4);
  float* L1 = (float*)alloc((size_t)9*128*64*4);
  float* R1 = (float*)alloc((size_t)9*128*64*4);
  float* h1 = (float*)alloc((size_t)128*729*4);
  char* Tn1 = alloc((size_t)128*81*8192);
  char* Wn1 = alloc((size_t)128*81*8192);
  size_t need_r7 = off;
  char* Tn2 = alloc((size_t)128*9*8192);
  char* Wn2 = alloc((size_t)128*9*8192);
  char* GF  = alloc((size_t)128*10*8192);
  size_t need_full = off;
  bool full = (ws_size >= need_full);
  bool grp1 = (ws_size >= need_r7);
  (void)in_sizes; (void)n_in; (void)out_size;

  // streams
  k_build <<<1296,  256, 0, stream>>>(Wmid1, Wout1, S1L, 9, 81, 0);
  k_build <<<1296,  256, 0, stream>>>(Wmid1, Wout1, S1R, 9, 81, 1);
  k_buildF<<<1280,  256, 0, stream>>>(WmidF, SF);
  k_build<<<11664, 256, 0, stream>>>(Wmid0, Wout0, S0L, 81, 729, 0);
  k_build<<<11664, 256, 0, stream>>>(Wmid0, Wout0, S0R, 81, 729, 1);

  // layer 1
  k_embed<<<365, 256, 0, stream>>>(x, 81, 27, v0);
  if (grp1){
    k_prod <<<2592, 512, 0, stream>>>(S0L, S0R, v0, Tn1, Wn1, 81);
    k_gscan<<<256, 64, 0, stream>>>(Tn1, Wn1, v0, L0, R0, 81);
  } else {
    k_vrec <<<365, 256, 0, stream>>>(v0, S0L, 729, 729, 0);
    k_vrec <<<365, 256, 0, stream>>>(v0, S0R, 729, 729, 1);
    k_scan_m<<<8, 64, 0, stream>>>(S0L, S0R, L0, R0, 81, 729);
  }
  k_out<false><<<dim3(81,4), 256, 0, stream>>>(Wout0, L0, R0, v0, 729, h1, (float2*)nullptr);

  // layer 2
  k_embed<<<41, 256, 0, stream>>>(h1, 27, 9, v1);
  if (full){
    k_prod <<<288, 512, 0, stream>>>(S1L, S1R, v1, Tn2, Wn2, 9);
    k_gscan<<<256, 64, 0, stream>>>(Tn2, Wn2, v1, L1, R1, 9);
  } else {
    k_vrec <<<41, 256, 0, stream>>>(v1, S1L, 81, 81, 0);
    k_vrec <<<41, 256, 0, stream>>>(v1, S1R, 81, 81, 1);
    k_scan_m<<<8, 64, 0, stream>>>(S1L, S1R, L1, R1, 9, 81);
  }
  k_out<true><<<dim3(9,4), 256, 0, stream>>>(Wout1, L1, R1, v1, 81, (float*)nullptr, vF);

  // final layer
  if (full){
    k_prodF<<<160, 512, 0, stream>>>(SF, vF, GF);
    k_fscan<<<128, 64, 0, stream>>>(GF, A0f, vF, outp);
  } else {
    k_vrec <<<40, 256, 0, stream>>>(vF, SF, 80, 81, 2);
    k_final_m<<<40, 64, 0, stream>>>(SF, A0f, vF, outp);
  }
}